// Round 6
// baseline (1426.046 us; speedup 1.0000x reference)
//
#include <hip/hip_runtime.h>
#include <hip/hip_fp16.h>

typedef _Float16 half8 __attribute__((ext_vector_type(8)));
typedef float floatx4 __attribute__((ext_vector_type(4)));

// d_ws half-element layout (packed fragment-major fp16)
#define W1YH_OFF 0        // W1 y-half (K=0..63)  hi: 256x64
#define W1YL_OFF 16384    //                      lo
#define W1UH_OFF 32768    // W1 u-half (K=64..127) hi
#define W1UL_OFF 49152    //                       lo
#define W2H_OFF  65536    // W2 hi: 256x256
#define W2L_OFF  131072
#define W3H_OFF  196608   // W3 hi: 64x256
#define W3L_OFF  212992

__device__ __forceinline__ floatx4 mfma16(half8 a, half8 b, floatx4 c) {
    return __builtin_amdgcn_mfma_f32_16x16x32_f16(a, b, c, 0, 0, 0);
}

// Pack W[n][k] (row-major [N][K] fp32) into MFMA-B fragment-major fp16 hi/lo
__global__ __launch_bounds__(256) void pack_weights(
    const float* __restrict__ W1, const float* __restrict__ W2,
    const float* __restrict__ W3, _Float16* __restrict__ ws)
{
    int e = blockIdx.x * 256 + threadIdx.x;  // 0..114687
    const float* W;
    int K, NT, eb = e;
    if (e < 32768)      { W = W1; K = 128; NT = 16; }
    else if (e < 98304) { W = W2; K = 256; NT = 16; eb = e - 32768; }
    else                { W = W3; K = 256; NT = 4;  eb = e - 98304; }
    int j = eb & 7, l = (eb >> 3) & 63, t = eb >> 9;
    int tn = t % NT, kk = t / NT;
    int n = tn * 16 + (l & 15);
    int k = kk * 32 + ((l >> 4) * 8) + j;
    float wv = W[n * K + k];
    _Float16 hi = (_Float16)wv;
    _Float16 lo = (_Float16)(wv - (float)hi);
    int hoff, loff, fi;
    if (e < 32768) {            // W1: split y-half (kk<2) / u-half (kk>=2)
        if (kk < 2) { hoff = W1YH_OFF; loff = W1YL_OFF; fi = ((kk * 16 + tn) * 64 + l) * 8 + j; }
        else        { hoff = W1UH_OFF; loff = W1UL_OFF; fi = (((kk - 2) * 16 + tn) * 64 + l) * 8 + j; }
    } else if (e < 98304) { hoff = W2H_OFF; loff = W2L_OFF; fi = eb; }
    else                  { hoff = W3H_OFF; loff = W3L_OFF; fi = eb; }
    ws[hoff + fi] = hi;
    ws[loff + fi] = lo;
}

// K=64 tile: XOR (row&7)<<3 halfs -> 2-way max (free)
__device__ __forceinline__ half8 lds_frag64(const _Float16* s, int row, int k0) {
    int idx = (row * 64 + k0) ^ ((row & 7) << 3);
    return *reinterpret_cast<const half8*>(s + idx);
}
// K=256 tile: XOR (row&7)<<5 halfs (above the k-group bits) -> 2-way max
__device__ __forceinline__ half8 lds_frag256(const _Float16* s, int row, int k0) {
    int idx = (row * 256 + k0) ^ ((row & 7) << 5);
    return *reinterpret_cast<const half8*>(s + idx);
}

__global__ __launch_bounds__(512, 1) void ode_kernel(
    const float* __restrict__ x0, const float* __restrict__ u,
    const float* __restrict__ b1, const float* __restrict__ b2,
    const float* __restrict__ b3, const _Float16* __restrict__ ws,
    const int* __restrict__ t0p, const int* __restrict__ t1p,
    float* __restrict__ out)
{
    __shared__ _Float16 sW3h[16384], sW3l[16384];  // 32K + 32K
    __shared__ _Float16 sA1h[4096], sA1l[4096];    // 8K + 8K
    __shared__ _Float16 sA2h[4096], sA2l[4096];    // 8K + 8K
    __shared__ _Float16 sZh[1024], sZl[1024];      // 2K + 2K
    // total LDS = 102400 B -> 1 block/CU, 8 waves, 2/SIMD, VGPR cap 256

    const int tid = threadIdx.x;
    const int lane = tid & 63;
    const int w = tid >> 6;            // wave 0..7; owns N-tiles {2w, 2w+1}
    const int r0 = blockIdx.x * 16;
    const int arow = lane & 15;
    const int kb = (lane >> 4) * 8;
    const int q4 = (lane >> 4) * 4;
    const int t0n = 2 * w, t1n = 2 * w + 1;
    const int ocol = 16 * (w & 3) + arow;   // L3 C-frag col (valid on w<4)

    // ---- one-time LDS staging: W3 hi/lo ----
    {
        const half8* s3h = reinterpret_cast<const half8*>(ws + W3H_OFF);
        const half8* s3l = reinterpret_cast<const half8*>(ws + W3L_OFF);
        half8* d3h = reinterpret_cast<half8*>(sW3h);
        half8* d3l = reinterpret_cast<half8*>(sW3l);
        #pragma unroll
        for (int i = 0; i < 4; ++i) {
            d3h[tid + 512 * i] = s3h[tid + 512 * i];
            d3l[tid + 512 * i] = s3l[tid + 512 * i];
        }
    }
    // ---- fully register-resident weights (own 2 N-tiles each) ----
    half8 rW2h[2][8], rW2l[2][8], rW1h[2][2], rW1l[2][2];
    {
        const half8* g2h = reinterpret_cast<const half8*>(ws + W2H_OFF);
        const half8* g2l = reinterpret_cast<const half8*>(ws + W2L_OFF);
        const half8* g1h = reinterpret_cast<const half8*>(ws + W1YH_OFF);
        const half8* g1l = reinterpret_cast<const half8*>(ws + W1YL_OFF);
        #pragma unroll
        for (int t = 0; t < 2; ++t) {
            int tn = t0n + t;
            #pragma unroll
            for (int kk = 0; kk < 8; ++kk) {
                rW2h[t][kk] = g2h[(kk * 16 + tn) * 64 + lane];
                rW2l[t][kk] = g2l[(kk * 16 + tn) * 64 + lane];
            }
            #pragma unroll
            for (int kk = 0; kk < 2; ++kk) {
                rW1h[t][kk] = g1h[(kk * 16 + tn) * 64 + lane];
                rW1l[t][kk] = g1l[(kk * 16 + tn) * 64 + lane];
            }
        }
    }
    const float rB2a = b2[16 * t0n + arow], rB2b = b2[16 * t1n + arow];
    const float rB3 = b3[(w < 4) ? ocol : 0];

    // y state + k-history in C-frag registers (meaningful on w<4)
    float yv[4], kf[5][4];
    #pragma unroll
    for (int r = 0; r < 4; ++r)
        yv[r] = x0[(r0 + q4 + r) * 64 + ((w < 4) ? ocol : 0)];

    // ---- stage u (swizzled 16x64) into sA1 temporarily; z-y into sZ ----
    {
        int row = tid >> 5, c0 = (tid & 31) * 2;
        float u0v = u[(r0 + row) * 64 + c0], u1v = u[(r0 + row) * 64 + c0 + 1];
        float y0v = x0[(r0 + row) * 64 + c0], y1v = x0[(r0 + row) * 64 + c0 + 1];
        int idx = (row * 64 + c0) ^ ((row & 7) << 3);
        _Float16 g0 = (_Float16)u0v, g1 = (_Float16)u1v;
        sA1h[idx] = g0; sA1h[idx + 1] = g1;
        sA1l[idx] = (_Float16)(u0v - (float)g0);
        sA1l[idx + 1] = (_Float16)(u1v - (float)g1);
        _Float16 h0 = (_Float16)y0v, h1 = (_Float16)y1v;
        sZh[idx] = h0; sZh[idx + 1] = h1;
        sZl[idx] = (_Float16)(y0v - (float)h0);
        sZl[idx + 1] = (_Float16)(y1v - (float)h1);
    }
    __syncthreads();

    // ---- precompute cU = u @ W1u^T + b1 for both owned tiles (one-time) ----
    float cU[2][4];
    {
        const half8* guh = reinterpret_cast<const half8*>(ws + W1UH_OFF);
        const half8* gul = reinterpret_cast<const half8*>(ws + W1UL_OFF);
        #pragma unroll
        for (int t = 0; t < 2; ++t) {
            int tn = t0n + t;
            float b1v = b1[16 * tn + arow];
            floatx4 a0 = floatx4{b1v, b1v, b1v, b1v};
            floatx4 a1v = floatx4{0.f, 0.f, 0.f, 0.f};
            #pragma unroll
            for (int kk = 0; kk < 2; ++kk) {
                half8 ah = lds_frag64(sA1h, arow, kb + kk * 32);
                half8 al = lds_frag64(sA1l, arow, kb + kk * 32);
                half8 bh = guh[(kk * 16 + tn) * 64 + lane];
                half8 bl = gul[(kk * 16 + tn) * 64 + lane];
                floatx4& ac = kk ? a1v : a0;
                ac = mfma16(ah, bh, ac);
                ac = mfma16(ah, bl, ac);
                ac = mfma16(al, bh, ac);
            }
            #pragma unroll
            for (int r = 0; r < 4; ++r) cU[t][r] = a0[r] + a1v[r];
        }
    }
    __syncthreads();  // done using sA1 as u-staging

    const int nsteps = (t1p[0] - t0p[0]) * 60;  // h = 60s = 1/60 hr
    const float H = 1.0f / 60.0f;

    constexpr float CF[6][6] = {
        {0.161f, 0.f, 0.f, 0.f, 0.f, 0.f},
        {-0.008480655492356989f, 0.335480655492357f, 0.f, 0.f, 0.f, 0.f},
        {2.8971530571054935f, -6.359448489975075f, 4.3622954328695815f, 0.f, 0.f, 0.f},
        {5.325864828439257f, -11.748883564062828f, 7.4955393428898365f, -0.09249506636175525f, 0.f, 0.f},
        {5.86145544294642f, -12.92096931784711f, 8.159367898576159f, -0.071584973281401f, -0.028269050394068383f, 0.f},
        {0.09646076681806523f, 0.01f, 0.4798896504144996f, 1.379008574103742f, -3.290069515436081f, 2.324710524099774f},
    };

    #pragma unroll 1
    for (int step = 0; step < nsteps; ++step) {
        #pragma unroll
        for (int stg = 0; stg < 6; ++stg) {
            // ---------- Phase A: L1 (z_y @ W1y^T + cU -> relu -> sA1), all-reg B ----------
            {
                half8 zh0 = lds_frag64(sZh, arow, kb);
                half8 zl0 = lds_frag64(sZl, arow, kb);
                half8 zh1 = lds_frag64(sZh, arow, kb + 32);
                half8 zl1 = lds_frag64(sZl, arow, kb + 32);
                #pragma unroll
                for (int t = 0; t < 2; ++t) {
                    floatx4 a0 = floatx4{cU[t][0], cU[t][1], cU[t][2], cU[t][3]};
                    floatx4 a1v = floatx4{0.f, 0.f, 0.f, 0.f};
                    a0  = mfma16(zh0, rW1h[t][0], a0);
                    a0  = mfma16(zh0, rW1l[t][0], a0);
                    a0  = mfma16(zl0, rW1h[t][0], a0);
                    a1v = mfma16(zh1, rW1h[t][1], a1v);
                    a1v = mfma16(zh1, rW1l[t][1], a1v);
                    a1v = mfma16(zl1, rW1h[t][1], a1v);
                    int col = 16 * (t0n + t) + arow;
                    #pragma unroll
                    for (int r = 0; r < 4; ++r) {
                        int orow = q4 + r;
                        float v = fmaxf(a0[r] + a1v[r], 0.f);
                        _Float16 hi = (_Float16)v, lo = (_Float16)(v - (float)hi);
                        int idx = (orow * 256 + col) ^ ((orow & 7) << 5);
                        sA1h[idx] = hi;
                        sA1l[idx] = lo;
                    }
                }
            }
            __syncthreads();
            // ---------- Phase B: L2 (a1 @ W2^T -> relu -> sA2), W2 fully in regs ----------
            {
                floatx4 acc[2][2];
                acc[0][0] = floatx4{rB2a, rB2a, rB2a, rB2a};
                acc[0][1] = floatx4{0.f, 0.f, 0.f, 0.f};
                acc[1][0] = floatx4{rB2b, rB2b, rB2b, rB2b};
                acc[1][1] = floatx4{0.f, 0.f, 0.f, 0.f};
                #pragma unroll
                for (int kk = 0; kk < 8; ++kk) {
                    half8 ah = lds_frag256(sA1h, arow, kb + kk * 32);
                    half8 al = lds_frag256(sA1l, arow, kb + kk * 32);
                    acc[0][kk & 1] = mfma16(ah, rW2h[0][kk], acc[0][kk & 1]);
                    acc[0][kk & 1] = mfma16(ah, rW2l[0][kk], acc[0][kk & 1]);
                    acc[0][kk & 1] = mfma16(al, rW2h[0][kk], acc[0][kk & 1]);
                    acc[1][kk & 1] = mfma16(ah, rW2h[1][kk], acc[1][kk & 1]);
                    acc[1][kk & 1] = mfma16(ah, rW2l[1][kk], acc[1][kk & 1]);
                    acc[1][kk & 1] = mfma16(al, rW2h[1][kk], acc[1][kk & 1]);
                }
                #pragma unroll
                for (int t = 0; t < 2; ++t) {
                    int col = 16 * (t0n + t) + arow;
                    #pragma unroll
                    for (int r = 0; r < 4; ++r) {
                        int orow = q4 + r;
                        float v = fmaxf(acc[t][0][r] + acc[t][1][r], 0.f);
                        _Float16 hi = (_Float16)v, lo = (_Float16)(v - (float)hi);
                        int idx = (orow * 256 + col) ^ ((orow & 7) << 5);
                        sA2h[idx] = hi;
                        sA2l[idx] = lo;
                    }
                }
            }
            __syncthreads();
            // ---------- Phase C: L3 + RK combine (waves 0-3; k-history in regs) ----------
            if (w < 4) {
                floatx4 aE = floatx4{rB3, rB3, rB3, rB3};
                floatx4 aO = floatx4{0.f, 0.f, 0.f, 0.f};
                #pragma unroll
                for (int kk = 0; kk < 8; ++kk) {
                    half8 ah = lds_frag256(sA2h, arow, kb + kk * 32);
                    half8 al = lds_frag256(sA2l, arow, kb + kk * 32);
                    half8 bh = *reinterpret_cast<const half8*>(
                        sW3h + ((kk * 4 + w) * 64 + lane) * 8);
                    half8 bl = *reinterpret_cast<const half8*>(
                        sW3l + ((kk * 4 + w) * 64 + lane) * 8);
                    floatx4& ac = (kk & 1) ? aO : aE;
                    ac = mfma16(ah, bh, ac);
                    ac = mfma16(ah, bl, ac);
                    ac = mfma16(al, bh, ac);
                }
                // combine: z = y + H*(sum_{j<stg} c_j*kf_j + c_stg*k_new)
                #pragma unroll
                for (int r = 0; r < 4; ++r) {
                    int orow = q4 + r;
                    float kc = aE[r] + aO[r];
                    float s = CF[stg][stg] * kc;
                    #pragma unroll
                    for (int j = 0; j < stg; ++j)
                        s += CF[stg][j] * kf[j][r];
                    float z = yv[r] + H * s;
                    if (stg < 5) kf[stg][r] = kc;
                    else yv[r] = z;  // final combine of the step
                    int idx = (orow * 64 + ocol) ^ ((orow & 7) << 3);
                    _Float16 h0 = (_Float16)z;
                    sZh[idx] = h0;
                    sZl[idx] = (_Float16)(z - (float)h0);
                }
            }
            __syncthreads();
        }
    }
    // ---- write y_final from registers ----
    if (w < 4) {
        #pragma unroll
        for (int r = 0; r < 4; ++r)
            out[(r0 + q4 + r) * 64 + ocol] = yv[r];
    }
}

extern "C" void kernel_launch(void* const* d_in, const int* in_sizes, int n_in,
                              void* d_out, int out_size, void* d_ws, size_t ws_size,
                              hipStream_t stream)
{
    const float* x0 = (const float*)d_in[0];
    const float* u  = (const float*)d_in[1];
    const float* W1 = (const float*)d_in[2];
    const float* b1 = (const float*)d_in[3];
    const float* W2 = (const float*)d_in[4];
    const float* b2 = (const float*)d_in[5];
    const float* W3 = (const float*)d_in[6];
    const float* b3 = (const float*)d_in[7];
    const int* t0 = (const int*)d_in[8];
    const int* t1 = (const int*)d_in[9];
    float* out = (float*)d_out;
    _Float16* ws = (_Float16*)d_ws;

    pack_weights<<<448, 256, 0, stream>>>(W1, W2, W3, ws);
    ode_kernel<<<64, 512, 0, stream>>>(x0, u, b1, b2, b3, ws, t0, t1, out);
}

// Round 7
// 916.586 us; speedup vs baseline: 1.5558x; 1.5558x over previous
//
#include <hip/hip_runtime.h>
#include <hip/hip_fp16.h>

typedef _Float16 half8 __attribute__((ext_vector_type(8)));
typedef float floatx4 __attribute__((ext_vector_type(4)));

// d_ws half-element layout (packed fragment-major fp16)
#define W1YH_OFF 0        // W1 y-half (K=0..63)  hi: 256x64
#define W1YL_OFF 16384    //                      lo
#define W1UH_OFF 32768    // W1 u-half (K=64..127) hi
#define W1UL_OFF 49152    //                       lo
#define W2H_OFF  65536    // W2 hi: 256x256
#define W2L_OFF  131072
#define W3H_OFF  196608   // W3 hi: 64x256
#define W3L_OFF  212992

__device__ __forceinline__ floatx4 mfma16(half8 a, half8 b, floatx4 c) {
    return __builtin_amdgcn_mfma_f32_16x16x32_f16(a, b, c, 0, 0, 0);
}

// Pack W[n][k] (row-major [N][K] fp32) into MFMA-B fragment-major fp16 hi/lo
__global__ __launch_bounds__(256) void pack_weights(
    const float* __restrict__ W1, const float* __restrict__ W2,
    const float* __restrict__ W3, _Float16* __restrict__ ws)
{
    int e = blockIdx.x * 256 + threadIdx.x;  // 0..114687
    const float* W;
    int K, NT, eb = e;
    if (e < 32768)      { W = W1; K = 128; NT = 16; }
    else if (e < 98304) { W = W2; K = 256; NT = 16; eb = e - 32768; }
    else                { W = W3; K = 256; NT = 4;  eb = e - 98304; }
    int j = eb & 7, l = (eb >> 3) & 63, t = eb >> 9;
    int tn = t % NT, kk = t / NT;
    int n = tn * 16 + (l & 15);
    int k = kk * 32 + ((l >> 4) * 8) + j;
    float wv = W[n * K + k];
    _Float16 hi = (_Float16)wv;
    _Float16 lo = (_Float16)(wv - (float)hi);
    int hoff, loff, fi;
    if (e < 32768) {            // W1: split y-half (kk<2) / u-half (kk>=2)
        if (kk < 2) { hoff = W1YH_OFF; loff = W1YL_OFF; fi = ((kk * 16 + tn) * 64 + l) * 8 + j; }
        else        { hoff = W1UH_OFF; loff = W1UL_OFF; fi = (((kk - 2) * 16 + tn) * 64 + l) * 8 + j; }
    } else if (e < 98304) { hoff = W2H_OFF; loff = W2L_OFF; fi = eb; }
    else                  { hoff = W3H_OFF; loff = W3L_OFF; fi = eb; }
    ws[hoff + fi] = hi;
    ws[loff + fi] = lo;
}

// Swizzle: XOR half-index with (row&12)<<2  (bytes: (row&12)<<3 in {0,32,64,96})
// -> spreads the 4 write-quads (orow bits 2-3) over 128B; 16B granules kept.
__device__ __forceinline__ int swzi(int row, int lin) {
    return lin ^ ((row & 12) << 2);
}
__device__ __forceinline__ half8 lds_frag64(const _Float16* s, int row, int k0) {
    return *reinterpret_cast<const half8*>(s + swzi(row, row * 64 + k0));
}
__device__ __forceinline__ half8 lds_frag256(const _Float16* s, int row, int k0) {
    return *reinterpret_cast<const half8*>(s + swzi(row, row * 256 + k0));
}

__global__ __launch_bounds__(512) void ode_kernel(
    const float* __restrict__ x0, const float* __restrict__ u,
    const float* __restrict__ b1, const float* __restrict__ b2,
    const float* __restrict__ b3, const _Float16* __restrict__ ws,
    const int* __restrict__ t0p, const int* __restrict__ t1p,
    float* __restrict__ out)
{
    __shared__ _Float16 sW3h[16384];               // 32K: W3-hi packed
    __shared__ _Float16 sW1yh[16384];              // 32K: W1y-hi packed
    __shared__ _Float16 sA1h[4096], sA1l[4096];    // 8K + 8K
    __shared__ _Float16 sA2h[4096], sA2l[4096];    // 8K + 8K
    __shared__ _Float16 sZh[1024], sZl[1024];      // 2K + 2K
    __shared__ float sKf[5120];                    // 20K: k1..k5 C-frag layout
    // total LDS = 122880 B

    const int tid = threadIdx.x;
    const int lane = tid & 63;
    const int w = tid >> 6;            // wave 0..7; owns N-tiles {2w, 2w+1}
    const int r0 = blockIdx.x * 16;
    const int arow = lane & 15;
    const int kb = (lane >> 4) * 8;
    const int q4 = (lane >> 4) * 4;
    const int t0n = 2 * w, t1n = 2 * w + 1;
    const int ocol = 16 * (w & 3) + arow;   // L3 C-frag col (valid on w<4)

    // ---- one-time LDS staging: W3-hi + W1y-hi (4096 half8) ----
    {
        const half8* s3h = reinterpret_cast<const half8*>(ws + W3H_OFF);
        const half8* s1h = reinterpret_cast<const half8*>(ws + W1YH_OFF);
        half8* d3h = reinterpret_cast<half8*>(sW3h);
        half8* d1h = reinterpret_cast<half8*>(sW1yh);
        #pragma unroll
        for (int i = 0; i < 4; ++i) {
            d3h[tid + 512 * i] = s3h[tid + 512 * i];
            d1h[tid + 512 * i] = s1h[tid + 512 * i];
        }
    }
    // ---- register-resident W2-hi (own 2 N-tiles) ----
    half8 rW2h[2][8];
    {
        const half8* g2h = reinterpret_cast<const half8*>(ws + W2H_OFF);
        #pragma unroll
        for (int kk = 0; kk < 8; ++kk) {
            rW2h[0][kk] = g2h[(kk * 16 + t0n) * 64 + lane];
            rW2h[1][kk] = g2h[(kk * 16 + t1n) * 64 + lane];
        }
    }
    const float rB2a = b2[16 * t0n + arow], rB2b = b2[16 * t1n + arow];
    const float rB3 = b3[(w < 4) ? ocol : 0];

    // y state in C-frag registers (meaningful on w<4)
    float yv[4];
    #pragma unroll
    for (int r = 0; r < 4; ++r)
        yv[r] = x0[(r0 + q4 + r) * 64 + ((w < 4) ? ocol : 0)];

    // ---- stage u (hi/lo, swizzled 16x64) into sA1 temp; z-y into sZ ----
    {
        int row = tid >> 5, c0 = (tid & 31) * 2;
        float u0v = u[(r0 + row) * 64 + c0], u1v = u[(r0 + row) * 64 + c0 + 1];
        float y0v = x0[(r0 + row) * 64 + c0], y1v = x0[(r0 + row) * 64 + c0 + 1];
        int idx = swzi(row, row * 64 + c0);
        _Float16 g0 = (_Float16)u0v, g1 = (_Float16)u1v;
        sA1h[idx] = g0; sA1h[idx + 1] = g1;
        sA1l[idx] = (_Float16)(u0v - (float)g0);
        sA1l[idx + 1] = (_Float16)(u1v - (float)g1);
        _Float16 h0 = (_Float16)y0v, h1 = (_Float16)y1v;
        sZh[idx] = h0; sZh[idx + 1] = h1;
        sZl[idx] = (_Float16)(y0v - (float)h0);
        sZl[idx + 1] = (_Float16)(y1v - (float)h1);
    }
    __syncthreads();

    // ---- precompute cU = u @ W1u^T + b1 (hi+lo, one-time) ----
    float cU[2][4];
    {
        const half8* guh = reinterpret_cast<const half8*>(ws + W1UH_OFF);
        const half8* gul = reinterpret_cast<const half8*>(ws + W1UL_OFF);
        #pragma unroll
        for (int t = 0; t < 2; ++t) {
            int tn = t0n + t;
            float b1v = b1[16 * tn + arow];
            floatx4 a0 = floatx4{b1v, b1v, b1v, b1v};
            floatx4 a1v = floatx4{0.f, 0.f, 0.f, 0.f};
            #pragma unroll
            for (int kk = 0; kk < 2; ++kk) {
                half8 ah = lds_frag64(sA1h, arow, kb + kk * 32);
                half8 al = lds_frag64(sA1l, arow, kb + kk * 32);
                half8 bh = guh[(kk * 16 + tn) * 64 + lane];
                half8 bl = gul[(kk * 16 + tn) * 64 + lane];
                floatx4& ac = kk ? a1v : a0;
                ac = mfma16(ah, bh, ac);
                ac = mfma16(ah, bl, ac);
                ac = mfma16(al, bh, ac);
            }
            #pragma unroll
            for (int r = 0; r < 4; ++r) cU[t][r] = a0[r] + a1v[r];
        }
    }
    __syncthreads();  // done using sA1 as u-staging

    const int nsteps = (t1p[0] - t0p[0]) * 60;  // h = 60s = 1/60 hr
    const float H = 1.0f / 60.0f;

    constexpr float CF[6][6] = {
        {0.161f, 0.f, 0.f, 0.f, 0.f, 0.f},
        {-0.008480655492356989f, 0.335480655492357f, 0.f, 0.f, 0.f, 0.f},
        {2.8971530571054935f, -6.359448489975075f, 4.3622954328695815f, 0.f, 0.f, 0.f},
        {5.325864828439257f, -11.748883564062828f, 7.4955393428898365f, -0.09249506636175525f, 0.f, 0.f},
        {5.86145544294642f, -12.92096931784711f, 8.159367898576159f, -0.071584973281401f, -0.028269050394068383f, 0.f},
        {0.09646076681806523f, 0.01f, 0.4798896504144996f, 1.379008574103742f, -3.290069515436081f, 2.324710524099774f},
    };

    #pragma unroll 1
    for (int step = 0; step < nsteps; ++step) {
        #pragma unroll
        for (int stg = 0; stg < 6; ++stg) {
            // ---------- Phase A: L1 (z_y @ W1y-hi^T + cU -> relu -> sA1) ----------
            {
                half8 zh0 = lds_frag64(sZh, arow, kb);
                half8 zl0 = lds_frag64(sZl, arow, kb);
                half8 zh1 = lds_frag64(sZh, arow, kb + 32);
                half8 zl1 = lds_frag64(sZl, arow, kb + 32);
                #pragma unroll
                for (int t = 0; t < 2; ++t) {
                    int tn = t0n + t;
                    half8 b0 = *reinterpret_cast<const half8*>(
                        sW1yh + ((0 * 16 + tn) * 64 + lane) * 8);
                    half8 b1f = *reinterpret_cast<const half8*>(
                        sW1yh + ((1 * 16 + tn) * 64 + lane) * 8);
                    floatx4 a0 = floatx4{cU[t][0], cU[t][1], cU[t][2], cU[t][3]};
                    floatx4 a1v = floatx4{0.f, 0.f, 0.f, 0.f};
                    a0  = mfma16(zh0, b0, a0);
                    a0  = mfma16(zl0, b0, a0);
                    a1v = mfma16(zh1, b1f, a1v);
                    a1v = mfma16(zl1, b1f, a1v);
                    int col = 16 * tn + arow;
                    #pragma unroll
                    for (int r = 0; r < 4; ++r) {
                        int orow = q4 + r;
                        float v = fmaxf(a0[r] + a1v[r], 0.f);
                        _Float16 hi = (_Float16)v, lo = (_Float16)(v - (float)hi);
                        int idx = swzi(orow, orow * 256 + col);
                        sA1h[idx] = hi;
                        sA1l[idx] = lo;
                    }
                }
            }
            __syncthreads();
            // ---------- Phase B: L2 (a1 @ W2-hi^T -> relu -> sA2), W2 in regs ----------
            {
                floatx4 acc[2][2];
                acc[0][0] = floatx4{rB2a, rB2a, rB2a, rB2a};
                acc[0][1] = floatx4{0.f, 0.f, 0.f, 0.f};
                acc[1][0] = floatx4{rB2b, rB2b, rB2b, rB2b};
                acc[1][1] = floatx4{0.f, 0.f, 0.f, 0.f};
                #pragma unroll
                for (int kk = 0; kk < 8; ++kk) {
                    half8 ah = lds_frag256(sA1h, arow, kb + kk * 32);
                    half8 al = lds_frag256(sA1l, arow, kb + kk * 32);
                    acc[0][kk & 1] = mfma16(ah, rW2h[0][kk], acc[0][kk & 1]);
                    acc[0][kk & 1] = mfma16(al, rW2h[0][kk], acc[0][kk & 1]);
                    acc[1][kk & 1] = mfma16(ah, rW2h[1][kk], acc[1][kk & 1]);
                    acc[1][kk & 1] = mfma16(al, rW2h[1][kk], acc[1][kk & 1]);
                }
                #pragma unroll
                for (int t = 0; t < 2; ++t) {
                    int col = 16 * (t0n + t) + arow;
                    #pragma unroll
                    for (int r = 0; r < 4; ++r) {
                        int orow = q4 + r;
                        float v = fmaxf(acc[t][0][r] + acc[t][1][r], 0.f);
                        _Float16 hi = (_Float16)v, lo = (_Float16)(v - (float)hi);
                        int idx = swzi(orow, orow * 256 + col);
                        sA2h[idx] = hi;
                        sA2l[idx] = lo;
                    }
                }
            }
            __syncthreads();
            // ---------- Phase C: L3 (a2 @ W3-hi^T) + RK combine (waves 0-3) ----------
            if (w < 4) {
                floatx4 aE = floatx4{rB3, rB3, rB3, rB3};
                floatx4 aO = floatx4{0.f, 0.f, 0.f, 0.f};
                #pragma unroll
                for (int kk = 0; kk < 8; ++kk) {
                    half8 ah = lds_frag256(sA2h, arow, kb + kk * 32);
                    half8 al = lds_frag256(sA2l, arow, kb + kk * 32);
                    half8 bh = *reinterpret_cast<const half8*>(
                        sW3h + ((kk * 4 + w) * 64 + lane) * 8);
                    floatx4& ac = (kk & 1) ? aO : aE;
                    ac = mfma16(ah, bh, ac);
                    ac = mfma16(al, bh, ac);
                }
                // combine: z = y + H*(sum_{j<stg} c_j*k_j + c_stg*k_new)
                #pragma unroll
                for (int r = 0; r < 4; ++r) {
                    int orow = q4 + r;
                    float kc = aE[r] + aO[r];
                    float s = CF[stg][stg] * kc;
                    int kidx = (orow * 64 + ocol) ^ ((orow & 4) << 2);
                    #pragma unroll
                    for (int j = 0; j < stg; ++j)
                        s += CF[stg][j] * sKf[j * 1024 + kidx];
                    float z = yv[r] + H * s;
                    if (stg < 5) sKf[stg * 1024 + kidx] = kc;
                    else yv[r] = z;  // final combine of the step
                    int idx = swzi(orow, orow * 64 + ocol);
                    _Float16 h0 = (_Float16)z;
                    sZh[idx] = h0;
                    sZl[idx] = (_Float16)(z - (float)h0);
                }
            }
            __syncthreads();
        }
    }
    // ---- write y_final from registers ----
    if (w < 4) {
        #pragma unroll
        for (int r = 0; r < 4; ++r)
            out[(r0 + q4 + r) * 64 + ocol] = yv[r];
    }
}

extern "C" void kernel_launch(void* const* d_in, const int* in_sizes, int n_in,
                              void* d_out, int out_size, void* d_ws, size_t ws_size,
                              hipStream_t stream)
{
    const float* x0 = (const float*)d_in[0];
    const float* u  = (const float*)d_in[1];
    const float* W1 = (const float*)d_in[2];
    const float* b1 = (const float*)d_in[3];
    const float* W2 = (const float*)d_in[4];
    const float* b2 = (const float*)d_in[5];
    const float* W3 = (const float*)d_in[6];
    const float* b3 = (const float*)d_in[7];
    const int* t0 = (const int*)d_in[8];
    const int* t1 = (const int*)d_in[9];
    float* out = (float*)d_out;
    _Float16* ws = (_Float16*)d_ws;

    pack_weights<<<448, 256, 0, stream>>>(W1, W2, W3, ws);
    ode_kernel<<<64, 512, 0, stream>>>(x0, u, b1, b2, b3, ws, t0, t1, out);
}

// Round 8
// 714.878 us; speedup vs baseline: 1.9948x; 1.2822x over previous
//
#include <hip/hip_runtime.h>
#include <hip/hip_fp16.h>

typedef _Float16 half8 __attribute__((ext_vector_type(8)));
typedef float floatx4 __attribute__((ext_vector_type(4)));

// d_ws half-element layout (packed fragment-major fp16)
#define W1YH_OFF 0        // W1 y-half (K=0..63)  hi: 256x64
#define W1YL_OFF 16384    //                      lo
#define W1UH_OFF 32768    // W1 u-half (K=64..127) hi
#define W1UL_OFF 49152    //                       lo
#define W2H_OFF  65536    // W2 hi: 256x256
#define W2L_OFF  131072
#define W3H_OFF  196608   // W3 hi: 64x256
#define W3L_OFF  212992

__device__ __forceinline__ floatx4 mfma16(half8 a, half8 b, floatx4 c) {
    return __builtin_amdgcn_mfma_f32_16x16x32_f16(a, b, c, 0, 0, 0);
}

// Pack W[n][k] (row-major [N][K] fp32) into MFMA-B fragment-major fp16 hi/lo
__global__ __launch_bounds__(256) void pack_weights(
    const float* __restrict__ W1, const float* __restrict__ W2,
    const float* __restrict__ W3, _Float16* __restrict__ ws)
{
    int e = blockIdx.x * 256 + threadIdx.x;  // 0..114687
    const float* W;
    int K, NT, eb = e;
    if (e < 32768)      { W = W1; K = 128; NT = 16; }
    else if (e < 98304) { W = W2; K = 256; NT = 16; eb = e - 32768; }
    else                { W = W3; K = 256; NT = 4;  eb = e - 98304; }
    int j = eb & 7, l = (eb >> 3) & 63, t = eb >> 9;
    int tn = t % NT, kk = t / NT;
    int n = tn * 16 + (l & 15);
    int k = kk * 32 + ((l >> 4) * 8) + j;
    float wv = W[n * K + k];
    _Float16 hi = (_Float16)wv;
    _Float16 lo = (_Float16)(wv - (float)hi);
    int hoff, loff, fi;
    if (e < 32768) {            // W1: split y-half (kk<2) / u-half (kk>=2)
        if (kk < 2) { hoff = W1YH_OFF; loff = W1YL_OFF; fi = ((kk * 16 + tn) * 64 + l) * 8 + j; }
        else        { hoff = W1UH_OFF; loff = W1UL_OFF; fi = (((kk - 2) * 16 + tn) * 64 + l) * 8 + j; }
    } else if (e < 98304) { hoff = W2H_OFF; loff = W2L_OFF; fi = eb; }
    else                  { hoff = W3H_OFF; loff = W3L_OFF; fi = eb; }
    ws[hoff + fi] = hi;
    ws[loff + fi] = lo;
}

// Swizzle (half-element index XOR): ((row&7)<<3) ^ ((row&12)<<2)
// - b128 frag reads: per quarter-wave, nibble idx (row&7)^((row&12)>>1) covers
//   all 8 16B-nibbles exactly 2x -> uniform 2 dwords/bank = minimum.
// - b16 C-frag scatter writes: the 4 row-groups {r,4+r,8+r,12+r} map to 4
//   distinct 32B octets -> conflict-free.
// - XOR const < 64 halfs (row-local), 16B-granular (b128-safe), bijective.
__device__ __forceinline__ int swzi(int row, int lin) {
    return lin ^ (((row & 7) << 3) ^ ((row & 12) << 2));
}
__device__ __forceinline__ half8 lds_frag64(const _Float16* s, int row, int k0) {
    return *reinterpret_cast<const half8*>(s + swzi(row, row * 64 + k0));
}
__device__ __forceinline__ half8 lds_frag256(const _Float16* s, int row, int k0) {
    return *reinterpret_cast<const half8*>(s + swzi(row, row * 256 + k0));
}

__global__ __launch_bounds__(512) void ode_kernel(
    const float* __restrict__ x0, const float* __restrict__ u,
    const float* __restrict__ b1, const float* __restrict__ b2,
    const float* __restrict__ b3, const _Float16* __restrict__ ws,
    const int* __restrict__ t0p, const int* __restrict__ t1p,
    float* __restrict__ out)
{
    __shared__ _Float16 sW3h[16384];               // 32K: W3-hi packed
    __shared__ _Float16 sW1yh[16384];              // 32K: W1y-hi packed
    __shared__ _Float16 sA1h[4096], sA1l[4096];    // 8K + 8K
    __shared__ _Float16 sA2h[4096], sA2l[4096];    // 8K + 8K
    __shared__ _Float16 sZh[1024], sZl[1024];      // 2K + 2K
    __shared__ float sKf[5120];                    // 20K: k1..k5 C-frag layout
    // total LDS = 122880 B

    const int tid = threadIdx.x;
    const int lane = tid & 63;
    const int w = tid >> 6;            // wave 0..7; owns N-tiles {2w, 2w+1}
    const int r0 = blockIdx.x * 16;
    const int arow = lane & 15;
    const int kb = (lane >> 4) * 8;
    const int q4 = (lane >> 4) * 4;
    const int t0n = 2 * w, t1n = 2 * w + 1;
    const int ocol = 16 * (w & 3) + arow;   // L3 C-frag col (valid on w<4)

    // ---- one-time LDS staging: W3-hi + W1y-hi (4096 half8) ----
    {
        const half8* s3h = reinterpret_cast<const half8*>(ws + W3H_OFF);
        const half8* s1h = reinterpret_cast<const half8*>(ws + W1YH_OFF);
        half8* d3h = reinterpret_cast<half8*>(sW3h);
        half8* d1h = reinterpret_cast<half8*>(sW1yh);
        #pragma unroll
        for (int i = 0; i < 4; ++i) {
            d3h[tid + 512 * i] = s3h[tid + 512 * i];
            d1h[tid + 512 * i] = s1h[tid + 512 * i];
        }
    }
    // ---- register-resident W2-hi (own 2 N-tiles) ----
    half8 rW2h[2][8];
    {
        const half8* g2h = reinterpret_cast<const half8*>(ws + W2H_OFF);
        #pragma unroll
        for (int kk = 0; kk < 8; ++kk) {
            rW2h[0][kk] = g2h[(kk * 16 + t0n) * 64 + lane];
            rW2h[1][kk] = g2h[(kk * 16 + t1n) * 64 + lane];
        }
    }
    const float rB2a = b2[16 * t0n + arow], rB2b = b2[16 * t1n + arow];
    const float rB3 = b3[(w < 4) ? ocol : 0];

    // y state in C-frag registers (meaningful on w<4)
    float yv[4];
    #pragma unroll
    for (int r = 0; r < 4; ++r)
        yv[r] = x0[(r0 + q4 + r) * 64 + ((w < 4) ? ocol : 0)];

    // ---- stage u (hi/lo, swizzled 16x64) into sA1 temp; z-y into sZ ----
    {
        int row = tid >> 5, c0 = (tid & 31) * 2;
        float u0v = u[(r0 + row) * 64 + c0], u1v = u[(r0 + row) * 64 + c0 + 1];
        float y0v = x0[(r0 + row) * 64 + c0], y1v = x0[(r0 + row) * 64 + c0 + 1];
        int idx = swzi(row, row * 64 + c0);
        _Float16 g0 = (_Float16)u0v, g1 = (_Float16)u1v;
        sA1h[idx] = g0; sA1h[idx + 1] = g1;
        sA1l[idx] = (_Float16)(u0v - (float)g0);
        sA1l[idx + 1] = (_Float16)(u1v - (float)g1);
        _Float16 h0 = (_Float16)y0v, h1 = (_Float16)y1v;
        sZh[idx] = h0; sZh[idx + 1] = h1;
        sZl[idx] = (_Float16)(y0v - (float)h0);
        sZl[idx + 1] = (_Float16)(y1v - (float)h1);
    }
    __syncthreads();

    // ---- precompute cU = u @ W1u^T + b1 (hi+lo, one-time) ----
    float cU[2][4];
    {
        const half8* guh = reinterpret_cast<const half8*>(ws + W1UH_OFF);
        const half8* gul = reinterpret_cast<const half8*>(ws + W1UL_OFF);
        #pragma unroll
        for (int t = 0; t < 2; ++t) {
            int tn = t0n + t;
            float b1v = b1[16 * tn + arow];
            floatx4 a0 = floatx4{b1v, b1v, b1v, b1v};
            floatx4 a1v = floatx4{0.f, 0.f, 0.f, 0.f};
            #pragma unroll
            for (int kk = 0; kk < 2; ++kk) {
                half8 ah = lds_frag64(sA1h, arow, kb + kk * 32);
                half8 al = lds_frag64(sA1l, arow, kb + kk * 32);
                half8 bh = guh[(kk * 16 + tn) * 64 + lane];
                half8 bl = gul[(kk * 16 + tn) * 64 + lane];
                floatx4& ac = kk ? a1v : a0;
                ac = mfma16(ah, bh, ac);
                ac = mfma16(ah, bl, ac);
                ac = mfma16(al, bh, ac);
            }
            #pragma unroll
            for (int r = 0; r < 4; ++r) cU[t][r] = a0[r] + a1v[r];
        }
    }
    __syncthreads();  // done using sA1 as u-staging

    const int nsteps = (t1p[0] - t0p[0]) * 60;  // h = 60s = 1/60 hr
    const float H = 1.0f / 60.0f;

    constexpr float CF[6][6] = {
        {0.161f, 0.f, 0.f, 0.f, 0.f, 0.f},
        {-0.008480655492356989f, 0.335480655492357f, 0.f, 0.f, 0.f, 0.f},
        {2.8971530571054935f, -6.359448489975075f, 4.3622954328695815f, 0.f, 0.f, 0.f},
        {5.325864828439257f, -11.748883564062828f, 7.4955393428898365f, -0.09249506636175525f, 0.f, 0.f},
        {5.86145544294642f, -12.92096931784711f, 8.159367898576159f, -0.071584973281401f, -0.028269050394068383f, 0.f},
        {0.09646076681806523f, 0.01f, 0.4798896504144996f, 1.379008574103742f, -3.290069515436081f, 2.324710524099774f},
    };

    #pragma unroll 1
    for (int step = 0; step < nsteps; ++step) {
        #pragma unroll
        for (int stg = 0; stg < 6; ++stg) {
            // ---------- Phase A: L1 (z_y @ W1y-hi^T + cU -> relu -> sA1) ----------
            {
                half8 zh0 = lds_frag64(sZh, arow, kb);
                half8 zl0 = lds_frag64(sZl, arow, kb);
                half8 zh1 = lds_frag64(sZh, arow, kb + 32);
                half8 zl1 = lds_frag64(sZl, arow, kb + 32);
                #pragma unroll
                for (int t = 0; t < 2; ++t) {
                    int tn = t0n + t;
                    half8 b0 = *reinterpret_cast<const half8*>(
                        sW1yh + ((0 * 16 + tn) * 64 + lane) * 8);
                    half8 b1f = *reinterpret_cast<const half8*>(
                        sW1yh + ((1 * 16 + tn) * 64 + lane) * 8);
                    floatx4 a0 = floatx4{cU[t][0], cU[t][1], cU[t][2], cU[t][3]};
                    floatx4 a1v = floatx4{0.f, 0.f, 0.f, 0.f};
                    a0  = mfma16(zh0, b0, a0);
                    a0  = mfma16(zl0, b0, a0);
                    a1v = mfma16(zh1, b1f, a1v);
                    a1v = mfma16(zl1, b1f, a1v);
                    int col = 16 * tn + arow;
                    #pragma unroll
                    for (int r = 0; r < 4; ++r) {
                        int orow = q4 + r;
                        float v = fmaxf(a0[r] + a1v[r], 0.f);
                        _Float16 hi = (_Float16)v, lo = (_Float16)(v - (float)hi);
                        int idx = swzi(orow, orow * 256 + col);
                        sA1h[idx] = hi;
                        sA1l[idx] = lo;
                    }
                }
            }
            __syncthreads();
            // ---------- Phase B: L2 (a1 @ W2-hi^T -> relu -> sA2), W2 in regs ----------
            {
                floatx4 acc[2][2];
                acc[0][0] = floatx4{rB2a, rB2a, rB2a, rB2a};
                acc[0][1] = floatx4{0.f, 0.f, 0.f, 0.f};
                acc[1][0] = floatx4{rB2b, rB2b, rB2b, rB2b};
                acc[1][1] = floatx4{0.f, 0.f, 0.f, 0.f};
                #pragma unroll
                for (int kk = 0; kk < 8; ++kk) {
                    half8 ah = lds_frag256(sA1h, arow, kb + kk * 32);
                    half8 al = lds_frag256(sA1l, arow, kb + kk * 32);
                    acc[0][kk & 1] = mfma16(ah, rW2h[0][kk], acc[0][kk & 1]);
                    acc[0][kk & 1] = mfma16(al, rW2h[0][kk], acc[0][kk & 1]);
                    acc[1][kk & 1] = mfma16(ah, rW2h[1][kk], acc[1][kk & 1]);
                    acc[1][kk & 1] = mfma16(al, rW2h[1][kk], acc[1][kk & 1]);
                }
                #pragma unroll
                for (int t = 0; t < 2; ++t) {
                    int col = 16 * (t0n + t) + arow;
                    #pragma unroll
                    for (int r = 0; r < 4; ++r) {
                        int orow = q4 + r;
                        float v = fmaxf(acc[t][0][r] + acc[t][1][r], 0.f);
                        _Float16 hi = (_Float16)v, lo = (_Float16)(v - (float)hi);
                        int idx = swzi(orow, orow * 256 + col);
                        sA2h[idx] = hi;
                        sA2l[idx] = lo;
                    }
                }
            }
            __syncthreads();
            // ---------- Phase C: L3 (a2 @ W3-hi^T) + RK combine (waves 0-3) ----------
            if (w < 4) {
                floatx4 aE = floatx4{rB3, rB3, rB3, rB3};
                floatx4 aO = floatx4{0.f, 0.f, 0.f, 0.f};
                #pragma unroll
                for (int kk = 0; kk < 8; ++kk) {
                    half8 ah = lds_frag256(sA2h, arow, kb + kk * 32);
                    half8 al = lds_frag256(sA2l, arow, kb + kk * 32);
                    half8 bh = *reinterpret_cast<const half8*>(
                        sW3h + ((kk * 4 + w) * 64 + lane) * 8);
                    floatx4& ac = (kk & 1) ? aO : aE;
                    ac = mfma16(ah, bh, ac);
                    ac = mfma16(al, bh, ac);
                }
                // combine: z = y + H*(sum_{j<stg} c_j*k_j + c_stg*k_new)
                #pragma unroll
                for (int r = 0; r < 4; ++r) {
                    int orow = q4 + r;
                    float kc = aE[r] + aO[r];
                    float s = CF[stg][stg] * kc;
                    int kidx = (orow * 64 + ocol) ^ ((orow & 4) << 2);
                    #pragma unroll
                    for (int j = 0; j < stg; ++j)
                        s += CF[stg][j] * sKf[j * 1024 + kidx];
                    float z = yv[r] + H * s;
                    if (stg < 5) sKf[stg * 1024 + kidx] = kc;
                    else yv[r] = z;  // final combine of the step
                    int idx = swzi(orow, orow * 64 + ocol);
                    _Float16 h0 = (_Float16)z;
                    sZh[idx] = h0;
                    sZl[idx] = (_Float16)(z - (float)h0);
                }
            }
            __syncthreads();
        }
    }
    // ---- write y_final from registers ----
    if (w < 4) {
        #pragma unroll
        for (int r = 0; r < 4; ++r)
            out[(r0 + q4 + r) * 64 + ocol] = yv[r];
    }
}

extern "C" void kernel_launch(void* const* d_in, const int* in_sizes, int n_in,
                              void* d_out, int out_size, void* d_ws, size_t ws_size,
                              hipStream_t stream)
{
    const float* x0 = (const float*)d_in[0];
    const float* u  = (const float*)d_in[1];
    const float* W1 = (const float*)d_in[2];
    const float* b1 = (const float*)d_in[3];
    const float* W2 = (const float*)d_in[4];
    const float* b2 = (const float*)d_in[5];
    const float* W3 = (const float*)d_in[6];
    const float* b3 = (const float*)d_in[7];
    const int* t0 = (const int*)d_in[8];
    const int* t1 = (const int*)d_in[9];
    float* out = (float*)d_out;
    _Float16* ws = (_Float16*)d_ws;

    pack_weights<<<448, 256, 0, stream>>>(W1, W2, W3, ws);
    ode_kernel<<<64, 512, 0, stream>>>(x0, u, b1, b2, b3, ws, t0, t1, out);
}

// Round 9
// 448.464 us; speedup vs baseline: 3.1798x; 1.5941x over previous
//
#include <hip/hip_runtime.h>
#include <hip/hip_fp16.h>

typedef _Float16 half8 __attribute__((ext_vector_type(8)));
typedef float floatx4 __attribute__((ext_vector_type(4)));

// d_ws half-element layout (packed fragment-major fp16)
#define W1YH_OFF 0        // W1 y-half (K=0..63)  hi: 256x64
#define W1YL_OFF 16384    //                      lo
#define W1UH_OFF 32768    // W1 u-half (K=64..127) hi
#define W1UL_OFF 49152    //                       lo
#define W2H_OFF  65536    // W2 hi: 256x256
#define W2L_OFF  131072
#define W3H_OFF  196608   // W3 hi: 64x256
#define W3L_OFF  212992

__device__ __forceinline__ floatx4 mfma16(half8 a, half8 b, floatx4 c) {
    return __builtin_amdgcn_mfma_f32_16x16x32_f16(a, b, c, 0, 0, 0);
}

// Pack W[n][k] (row-major [N][K] fp32) into MFMA-B fragment-major fp16 hi/lo
__global__ __launch_bounds__(256) void pack_weights(
    const float* __restrict__ W1, const float* __restrict__ W2,
    const float* __restrict__ W3, _Float16* __restrict__ ws)
{
    int e = blockIdx.x * 256 + threadIdx.x;  // 0..114687
    const float* W;
    int K, NT, eb = e;
    if (e < 32768)      { W = W1; K = 128; NT = 16; }
    else if (e < 98304) { W = W2; K = 256; NT = 16; eb = e - 32768; }
    else                { W = W3; K = 256; NT = 4;  eb = e - 98304; }
    int j = eb & 7, l = (eb >> 3) & 63, t = eb >> 9;
    int tn = t % NT, kk = t / NT;
    int n = tn * 16 + (l & 15);
    int k = kk * 32 + ((l >> 4) * 8) + j;
    float wv = W[n * K + k];
    _Float16 hi = (_Float16)wv;
    _Float16 lo = (_Float16)(wv - (float)hi);
    int hoff, loff, fi;
    if (e < 32768) {            // W1: split y-half (kk<2) / u-half (kk>=2)
        if (kk < 2) { hoff = W1YH_OFF; loff = W1YL_OFF; fi = ((kk * 16 + tn) * 64 + l) * 8 + j; }
        else        { hoff = W1UH_OFF; loff = W1UL_OFF; fi = (((kk - 2) * 16 + tn) * 64 + l) * 8 + j; }
    } else if (e < 98304) { hoff = W2H_OFF; loff = W2L_OFF; fi = eb; }
    else                  { hoff = W3H_OFF; loff = W3L_OFF; fi = eb; }
    ws[hoff + fi] = hi;
    ws[loff + fi] = lo;
}

// Swizzle (half-element index XOR): ((row&7)<<3) ^ ((row&12)<<2)
// - b128 frag reads: per quarter-wave, 16B-nibble idx (row&7)^((row&12)>>1)
//   covers all 8 nibbles exactly 2x -> uniform 2 dwords/bank = minimum.
// - b16 C-frag scatter writes: row-groups {r,4+r,8+r,12+r} -> 4 distinct 32B
//   octets -> conflict-free. Row-local, 16B-granular, bijective.
__device__ __forceinline__ int swzi(int row, int lin) {
    return lin ^ (((row & 7) << 3) ^ ((row & 12) << 2));
}
__device__ __forceinline__ half8 lds_frag64(const _Float16* s, int row, int k0) {
    return *reinterpret_cast<const half8*>(s + swzi(row, row * 64 + k0));
}
__device__ __forceinline__ half8 lds_frag256(const _Float16* s, int row, int k0) {
    return *reinterpret_cast<const half8*>(s + swzi(row, row * 256 + k0));
}

__global__ __launch_bounds__(512) void ode_kernel(
    const float* __restrict__ x0, const float* __restrict__ u,
    const float* __restrict__ b1, const float* __restrict__ b2,
    const float* __restrict__ b3, const _Float16* __restrict__ ws,
    const int* __restrict__ t0p, const int* __restrict__ t1p,
    float* __restrict__ out)
{
    __shared__ _Float16 sW3h[16384];               // 32K: W3-hi packed
    __shared__ _Float16 sW1yh[16384];              // 32K: W1y-hi packed
    __shared__ _Float16 sA1h[4096];                // 8K  (activations fp16-only)
    __shared__ _Float16 sA2h[4096];                // 8K
    __shared__ _Float16 sZh[1024];                 // 2K
    __shared__ float sKf[5120];                    // 20K: k1..k5 C-frag layout
    // total LDS = 102400 B

    const int tid = threadIdx.x;
    const int lane = tid & 63;
    const int w = tid >> 6;            // wave 0..7; owns N-tiles {2w, 2w+1}
    const int r0 = blockIdx.x * 16;
    const int arow = lane & 15;
    const int kb = (lane >> 4) * 8;
    const int q4 = (lane >> 4) * 4;
    const int t0n = 2 * w, t1n = 2 * w + 1;
    const int ocol = 16 * (w & 3) + arow;   // L3 C-frag col (valid on w<4)

    // ---- one-time LDS staging: W3-hi + W1y-hi (4096 half8) ----
    {
        const half8* s3h = reinterpret_cast<const half8*>(ws + W3H_OFF);
        const half8* s1h = reinterpret_cast<const half8*>(ws + W1YH_OFF);
        half8* d3h = reinterpret_cast<half8*>(sW3h);
        half8* d1h = reinterpret_cast<half8*>(sW1yh);
        #pragma unroll
        for (int i = 0; i < 4; ++i) {
            d3h[tid + 512 * i] = s3h[tid + 512 * i];
            d1h[tid + 512 * i] = s1h[tid + 512 * i];
        }
    }
    // ---- register-resident W2-hi (own 2 N-tiles) ----
    half8 rW2h[2][8];
    {
        const half8* g2h = reinterpret_cast<const half8*>(ws + W2H_OFF);
        #pragma unroll
        for (int kk = 0; kk < 8; ++kk) {
            rW2h[0][kk] = g2h[(kk * 16 + t0n) * 64 + lane];
            rW2h[1][kk] = g2h[(kk * 16 + t1n) * 64 + lane];
        }
    }
    const float rB2a = b2[16 * t0n + arow], rB2b = b2[16 * t1n + arow];
    const float rB3 = b3[(w < 4) ? ocol : 0];

    // y state in C-frag registers (meaningful on w<4)
    float yv[4];
    #pragma unroll
    for (int r = 0; r < 4; ++r)
        yv[r] = x0[(r0 + q4 + r) * 64 + ((w < 4) ? ocol : 0)];

    // ---- stage u hi into sA1h, u lo into sA2h (temp); z-y hi into sZh ----
    {
        int row = tid >> 5, c0 = (tid & 31) * 2;
        float u0v = u[(r0 + row) * 64 + c0], u1v = u[(r0 + row) * 64 + c0 + 1];
        float y0v = x0[(r0 + row) * 64 + c0], y1v = x0[(r0 + row) * 64 + c0 + 1];
        int idx = swzi(row, row * 64 + c0);
        _Float16 g0 = (_Float16)u0v, g1 = (_Float16)u1v;
        sA1h[idx] = g0; sA1h[idx + 1] = g1;
        sA2h[idx] = (_Float16)(u0v - (float)g0);
        sA2h[idx + 1] = (_Float16)(u1v - (float)g1);
        sZh[idx] = (_Float16)y0v;
        sZh[idx + 1] = (_Float16)y1v;
    }
    __syncthreads();

    // ---- precompute cU = u @ W1u^T + b1 (hi+lo inputs, exact-ish, one-time) ----
    float cU[2][4];
    {
        const half8* guh = reinterpret_cast<const half8*>(ws + W1UH_OFF);
        const half8* gul = reinterpret_cast<const half8*>(ws + W1UL_OFF);
        #pragma unroll
        for (int t = 0; t < 2; ++t) {
            int tn = t0n + t;
            float b1v = b1[16 * tn + arow];
            floatx4 a0 = floatx4{b1v, b1v, b1v, b1v};
            floatx4 a1v = floatx4{0.f, 0.f, 0.f, 0.f};
            #pragma unroll
            for (int kk = 0; kk < 2; ++kk) {
                half8 ah = lds_frag64(sA1h, arow, kb + kk * 32);
                half8 al = lds_frag64(sA2h, arow, kb + kk * 32);
                half8 bh = guh[(kk * 16 + tn) * 64 + lane];
                half8 bl = gul[(kk * 16 + tn) * 64 + lane];
                floatx4& ac = kk ? a1v : a0;
                ac = mfma16(ah, bh, ac);
                ac = mfma16(ah, bl, ac);
                ac = mfma16(al, bh, ac);
            }
            #pragma unroll
            for (int r = 0; r < 4; ++r) cU[t][r] = a0[r] + a1v[r];
        }
    }
    __syncthreads();  // done using sA1h/sA2h as u-staging

    const int nsteps = (t1p[0] - t0p[0]) * 60;  // h = 60s = 1/60 hr
    const float H = 1.0f / 60.0f;

    constexpr float CF[6][6] = {
        {0.161f, 0.f, 0.f, 0.f, 0.f, 0.f},
        {-0.008480655492356989f, 0.335480655492357f, 0.f, 0.f, 0.f, 0.f},
        {2.8971530571054935f, -6.359448489975075f, 4.3622954328695815f, 0.f, 0.f, 0.f},
        {5.325864828439257f, -11.748883564062828f, 7.4955393428898365f, -0.09249506636175525f, 0.f, 0.f},
        {5.86145544294642f, -12.92096931784711f, 8.159367898576159f, -0.071584973281401f, -0.028269050394068383f, 0.f},
        {0.09646076681806523f, 0.01f, 0.4798896504144996f, 1.379008574103742f, -3.290069515436081f, 2.324710524099774f},
    };

    #pragma unroll 1
    for (int step = 0; step < nsteps; ++step) {
        #pragma unroll
        for (int stg = 0; stg < 6; ++stg) {
            // ---------- Phase A: L1 (z_y @ W1y-hi^T + cU -> relu -> sA1h) ----------
            {
                half8 zh0 = lds_frag64(sZh, arow, kb);
                half8 zh1 = lds_frag64(sZh, arow, kb + 32);
                #pragma unroll
                for (int t = 0; t < 2; ++t) {
                    int tn = t0n + t;
                    half8 b0 = *reinterpret_cast<const half8*>(
                        sW1yh + ((0 * 16 + tn) * 64 + lane) * 8);
                    half8 b1f = *reinterpret_cast<const half8*>(
                        sW1yh + ((1 * 16 + tn) * 64 + lane) * 8);
                    floatx4 a0 = floatx4{cU[t][0], cU[t][1], cU[t][2], cU[t][3]};
                    a0 = mfma16(zh0, b0, a0);
                    a0 = mfma16(zh1, b1f, a0);
                    int col = 16 * tn + arow;
                    #pragma unroll
                    for (int r = 0; r < 4; ++r) {
                        int orow = q4 + r;
                        float v = fmaxf(a0[r], 0.f);
                        sA1h[swzi(orow, orow * 256 + col)] = (_Float16)v;
                    }
                }
            }
            __syncthreads();
            // ---------- Phase B: L2 (a1 @ W2-hi^T -> relu -> sA2h), W2 in regs ----------
            {
                floatx4 acc[2][2];
                acc[0][0] = floatx4{rB2a, rB2a, rB2a, rB2a};
                acc[0][1] = floatx4{0.f, 0.f, 0.f, 0.f};
                acc[1][0] = floatx4{rB2b, rB2b, rB2b, rB2b};
                acc[1][1] = floatx4{0.f, 0.f, 0.f, 0.f};
                #pragma unroll
                for (int kk = 0; kk < 8; ++kk) {
                    half8 ah = lds_frag256(sA1h, arow, kb + kk * 32);
                    acc[0][kk & 1] = mfma16(ah, rW2h[0][kk], acc[0][kk & 1]);
                    acc[1][kk & 1] = mfma16(ah, rW2h[1][kk], acc[1][kk & 1]);
                }
                #pragma unroll
                for (int t = 0; t < 2; ++t) {
                    int col = 16 * (t0n + t) + arow;
                    #pragma unroll
                    for (int r = 0; r < 4; ++r) {
                        int orow = q4 + r;
                        float v = fmaxf(acc[t][0][r] + acc[t][1][r], 0.f);
                        sA2h[swzi(orow, orow * 256 + col)] = (_Float16)v;
                    }
                }
            }
            __syncthreads();
            // ---------- Phase C: L3 (a2 @ W3-hi^T) + RK combine (waves 0-3) ----------
            if (w < 4) {
                floatx4 aE = floatx4{rB3, rB3, rB3, rB3};
                floatx4 aO = floatx4{0.f, 0.f, 0.f, 0.f};
                #pragma unroll
                for (int kk = 0; kk < 8; ++kk) {
                    half8 ah = lds_frag256(sA2h, arow, kb + kk * 32);
                    half8 bh = *reinterpret_cast<const half8*>(
                        sW3h + ((kk * 4 + w) * 64 + lane) * 8);
                    floatx4& ac = (kk & 1) ? aO : aE;
                    ac = mfma16(ah, bh, ac);
                }
                // combine: z = y + H*(sum_{j<stg} c_j*k_j + c_stg*k_new)
                #pragma unroll
                for (int r = 0; r < 4; ++r) {
                    int orow = q4 + r;
                    float kc = aE[r] + aO[r];
                    float s = CF[stg][stg] * kc;
                    int kidx = (orow * 64 + ocol) ^ ((orow & 4) << 2);
                    #pragma unroll
                    for (int j = 0; j < stg; ++j)
                        s += CF[stg][j] * sKf[j * 1024 + kidx];
                    float z = yv[r] + H * s;
                    if (stg < 5) sKf[stg * 1024 + kidx] = kc;
                    else yv[r] = z;  // final combine of the step
                    sZh[swzi(orow, orow * 64 + ocol)] = (_Float16)z;
                }
            }
            __syncthreads();
        }
    }
    // ---- write y_final from registers ----
    if (w < 4) {
        #pragma unroll
        for (int r = 0; r < 4; ++r)
            out[(r0 + q4 + r) * 64 + ocol] = yv[r];
    }
}

extern "C" void kernel_launch(void* const* d_in, const int* in_sizes, int n_in,
                              void* d_out, int out_size, void* d_ws, size_t ws_size,
                              hipStream_t stream)
{
    const float* x0 = (const float*)d_in[0];
    const float* u  = (const float*)d_in[1];
    const float* W1 = (const float*)d_in[2];
    const float* b1 = (const float*)d_in[3];
    const float* W2 = (const float*)d_in[4];
    const float* b2 = (const float*)d_in[5];
    const float* W3 = (const float*)d_in[6];
    const float* b3 = (const float*)d_in[7];
    const int* t0 = (const int*)d_in[8];
    const int* t1 = (const int*)d_in[9];
    float* out = (float*)d_out;
    _Float16* ws = (_Float16*)d_ws;

    pack_weights<<<448, 256, 0, stream>>>(W1, W2, W3, ws);
    ode_kernel<<<64, 512, 0, stream>>>(x0, u, b1, b2, b3, ws, t0, t1, out);
}

// Round 10
// 390.005 us; speedup vs baseline: 3.6565x; 1.1499x over previous
//
#include <hip/hip_runtime.h>
#include <hip/hip_fp16.h>

typedef _Float16 half8 __attribute__((ext_vector_type(8)));
typedef float floatx4 __attribute__((ext_vector_type(4)));

// d_ws half-element layout (packed fragment-major fp16)
#define W1YH_OFF 0        // W1 y-half (K=0..63)  hi: 256x64
#define W1YL_OFF 16384    //                      lo
#define W1UH_OFF 32768    // W1 u-half (K=64..127) hi
#define W1UL_OFF 49152    //                       lo
#define W2H_OFF  65536    // W2 hi: 256x256
#define W2L_OFF  131072
#define W3H_OFF  196608   // W3 hi: 64x256
#define W3L_OFF  212992

__device__ __forceinline__ floatx4 mfma16(half8 a, half8 b, floatx4 c) {
    return __builtin_amdgcn_mfma_f32_16x16x32_f16(a, b, c, 0, 0, 0);
}

// Pack W[n][k] (row-major [N][K] fp32) into MFMA-B fragment-major fp16 hi/lo
__global__ __launch_bounds__(256) void pack_weights(
    const float* __restrict__ W1, const float* __restrict__ W2,
    const float* __restrict__ W3, _Float16* __restrict__ ws)
{
    int e = blockIdx.x * 256 + threadIdx.x;  // 0..114687
    const float* W;
    int K, NT, eb = e;
    if (e < 32768)      { W = W1; K = 128; NT = 16; }
    else if (e < 98304) { W = W2; K = 256; NT = 16; eb = e - 32768; }
    else                { W = W3; K = 256; NT = 4;  eb = e - 98304; }
    int j = eb & 7, l = (eb >> 3) & 63, t = eb >> 9;
    int tn = t % NT, kk = t / NT;
    int n = tn * 16 + (l & 15);
    int k = kk * 32 + ((l >> 4) * 8) + j;
    float wv = W[n * K + k];
    _Float16 hi = (_Float16)wv;
    _Float16 lo = (_Float16)(wv - (float)hi);
    int hoff, loff, fi;
    if (e < 32768) {            // W1: split y-half (kk<2) / u-half (kk>=2)
        if (kk < 2) { hoff = W1YH_OFF; loff = W1YL_OFF; fi = ((kk * 16 + tn) * 64 + l) * 8 + j; }
        else        { hoff = W1UH_OFF; loff = W1UL_OFF; fi = (((kk - 2) * 16 + tn) * 64 + l) * 8 + j; }
    } else if (e < 98304) { hoff = W2H_OFF; loff = W2L_OFF; fi = eb; }
    else                  { hoff = W3H_OFF; loff = W3L_OFF; fi = eb; }
    ws[hoff + fi] = hi;
    ws[loff + fi] = lo;
}

// Swizzle (half-element index XOR): ((row&7)<<3) ^ ((row&12)<<2)
// - b128 frag reads: per quarter-wave, 16B-nibble idx (row&7)^((row&12)>>1)
//   covers all 8 nibbles exactly 2x -> uniform 2 dwords/bank = minimum.
// - b16 C-frag scatter writes: row-groups {r,4+r,8+r,12+r} -> 4 distinct 32B
//   octets -> conflict-free. Row-local, 16B-granular, bijective.
__device__ __forceinline__ int swzi(int row, int lin) {
    return lin ^ (((row & 7) << 3) ^ ((row & 12) << 2));
}
__device__ __forceinline__ half8 lds_frag64(const _Float16* s, int row, int k0) {
    return *reinterpret_cast<const half8*>(s + swzi(row, row * 64 + k0));
}
__device__ __forceinline__ half8 lds_frag256(const _Float16* s, int row, int k0) {
    return *reinterpret_cast<const half8*>(s + swzi(row, row * 256 + k0));
}

__global__ __launch_bounds__(512) void ode_kernel(
    const float* __restrict__ x0, const float* __restrict__ u,
    const float* __restrict__ b1, const float* __restrict__ b2,
    const float* __restrict__ b3, const _Float16* __restrict__ ws,
    const int* __restrict__ t0p, const int* __restrict__ t1p,
    float* __restrict__ out)
{
    __shared__ _Float16 sW3h[16384];               // 32K: W3-hi packed
    __shared__ _Float16 sA1h[4096];                // 8K  (activations fp16-only)
    __shared__ _Float16 sA2h[4096];                // 8K
    __shared__ _Float16 sZh[1024];                 // 2K
    // total LDS = 51200 B

    const int tid = threadIdx.x;
    const int lane = tid & 63;
    const int w = tid >> 6;            // wave 0..7; owns N-tiles {2w, 2w+1}
    const int r0 = blockIdx.x * 16;
    const int arow = lane & 15;
    const int kb = (lane >> 4) * 8;
    const int q4 = (lane >> 4) * 4;
    const int t0n = 2 * w, t1n = 2 * w + 1;
    const int ocol = 16 * (w & 3) + arow;   // L3 C-frag col (valid on w<4)

    // ---- one-time LDS staging: W3-hi (2048 half8) ----
    {
        const half8* s3h = reinterpret_cast<const half8*>(ws + W3H_OFF);
        half8* d3h = reinterpret_cast<half8*>(sW3h);
        #pragma unroll
        for (int i = 0; i < 4; ++i)
            d3h[tid + 512 * i] = s3h[tid + 512 * i];
    }
    // ---- register-resident: W2-hi (2 N-tiles) + W1y-hi (2 N-tiles) ----
    half8 rW2h[2][8], rW1h[2][2];
    {
        const half8* g2h = reinterpret_cast<const half8*>(ws + W2H_OFF);
        const half8* g1h = reinterpret_cast<const half8*>(ws + W1YH_OFF);
        #pragma unroll
        for (int kk = 0; kk < 8; ++kk) {
            rW2h[0][kk] = g2h[(kk * 16 + t0n) * 64 + lane];
            rW2h[1][kk] = g2h[(kk * 16 + t1n) * 64 + lane];
        }
        #pragma unroll
        for (int t = 0; t < 2; ++t)
            #pragma unroll
            for (int kk = 0; kk < 2; ++kk)
                rW1h[t][kk] = g1h[(kk * 16 + t0n + t) * 64 + lane];
    }
    const float rB2a = b2[16 * t0n + arow], rB2b = b2[16 * t1n + arow];
    const float rB3 = b3[(w < 4) ? ocol : 0];

    // y state + k-history in C-frag registers (meaningful on w<4)
    float yv[4], kf[5][4];
    #pragma unroll
    for (int r = 0; r < 4; ++r)
        yv[r] = x0[(r0 + q4 + r) * 64 + ((w < 4) ? ocol : 0)];

    // ---- stage u hi into sA1h, u lo into sA2h (temp); z-y hi into sZh ----
    {
        int row = tid >> 5, c0 = (tid & 31) * 2;
        float u0v = u[(r0 + row) * 64 + c0], u1v = u[(r0 + row) * 64 + c0 + 1];
        float y0v = x0[(r0 + row) * 64 + c0], y1v = x0[(r0 + row) * 64 + c0 + 1];
        int idx = swzi(row, row * 64 + c0);
        _Float16 g0 = (_Float16)u0v, g1 = (_Float16)u1v;
        sA1h[idx] = g0; sA1h[idx + 1] = g1;
        sA2h[idx] = (_Float16)(u0v - (float)g0);
        sA2h[idx + 1] = (_Float16)(u1v - (float)g1);
        sZh[idx] = (_Float16)y0v;
        sZh[idx + 1] = (_Float16)y1v;
    }
    __syncthreads();

    // ---- precompute cU = u @ W1u^T + b1 (hi+lo inputs, one-time) ----
    float cU[2][4];
    {
        const half8* guh = reinterpret_cast<const half8*>(ws + W1UH_OFF);
        const half8* gul = reinterpret_cast<const half8*>(ws + W1UL_OFF);
        #pragma unroll
        for (int t = 0; t < 2; ++t) {
            int tn = t0n + t;
            float b1v = b1[16 * tn + arow];
            floatx4 a0 = floatx4{b1v, b1v, b1v, b1v};
            floatx4 a1v = floatx4{0.f, 0.f, 0.f, 0.f};
            #pragma unroll
            for (int kk = 0; kk < 2; ++kk) {
                half8 ah = lds_frag64(sA1h, arow, kb + kk * 32);
                half8 al = lds_frag64(sA2h, arow, kb + kk * 32);
                half8 bh = guh[(kk * 16 + tn) * 64 + lane];
                half8 bl = gul[(kk * 16 + tn) * 64 + lane];
                floatx4& ac = kk ? a1v : a0;
                ac = mfma16(ah, bh, ac);
                ac = mfma16(ah, bl, ac);
                ac = mfma16(al, bh, ac);
            }
            #pragma unroll
            for (int r = 0; r < 4; ++r) cU[t][r] = a0[r] + a1v[r];
        }
    }
    __syncthreads();  // done using sA1h/sA2h as u-staging

    const int nsteps = (t1p[0] - t0p[0]) * 60;  // h = 60s = 1/60 hr
    const float H = 1.0f / 60.0f;

    constexpr float CF[6][6] = {
        {0.161f, 0.f, 0.f, 0.f, 0.f, 0.f},
        {-0.008480655492356989f, 0.335480655492357f, 0.f, 0.f, 0.f, 0.f},
        {2.8971530571054935f, -6.359448489975075f, 4.3622954328695815f, 0.f, 0.f, 0.f},
        {5.325864828439257f, -11.748883564062828f, 7.4955393428898365f, -0.09249506636175525f, 0.f, 0.f},
        {5.86145544294642f, -12.92096931784711f, 8.159367898576159f, -0.071584973281401f, -0.028269050394068383f, 0.f},
        {0.09646076681806523f, 0.01f, 0.4798896504144996f, 1.379008574103742f, -3.290069515436081f, 2.324710524099774f},
    };

    #pragma unroll 1
    for (int step = 0; step < nsteps; ++step) {
        #pragma unroll
        for (int stg = 0; stg < 6; ++stg) {
            // ---------- Phase A: L1 (z_y @ W1y-hi^T + cU -> relu -> sA1h), all-reg B ----------
            {
                half8 zh0 = lds_frag64(sZh, arow, kb);
                half8 zh1 = lds_frag64(sZh, arow, kb + 32);
                #pragma unroll
                for (int t = 0; t < 2; ++t) {
                    floatx4 a0 = floatx4{cU[t][0], cU[t][1], cU[t][2], cU[t][3]};
                    a0 = mfma16(zh0, rW1h[t][0], a0);
                    a0 = mfma16(zh1, rW1h[t][1], a0);
                    int col = 16 * (t0n + t) + arow;
                    #pragma unroll
                    for (int r = 0; r < 4; ++r) {
                        int orow = q4 + r;
                        float v = fmaxf(a0[r], 0.f);
                        sA1h[swzi(orow, orow * 256 + col)] = (_Float16)v;
                    }
                }
            }
            __syncthreads();
            // ---------- Phase B: L2 (a1 @ W2-hi^T -> relu -> sA2h), W2 in regs ----------
            {
                floatx4 acc[2][2];
                acc[0][0] = floatx4{rB2a, rB2a, rB2a, rB2a};
                acc[0][1] = floatx4{0.f, 0.f, 0.f, 0.f};
                acc[1][0] = floatx4{rB2b, rB2b, rB2b, rB2b};
                acc[1][1] = floatx4{0.f, 0.f, 0.f, 0.f};
                #pragma unroll
                for (int kk = 0; kk < 8; ++kk) {
                    half8 ah = lds_frag256(sA1h, arow, kb + kk * 32);
                    acc[0][kk & 1] = mfma16(ah, rW2h[0][kk], acc[0][kk & 1]);
                    acc[1][kk & 1] = mfma16(ah, rW2h[1][kk], acc[1][kk & 1]);
                }
                #pragma unroll
                for (int t = 0; t < 2; ++t) {
                    int col = 16 * (t0n + t) + arow;
                    #pragma unroll
                    for (int r = 0; r < 4; ++r) {
                        int orow = q4 + r;
                        float v = fmaxf(acc[t][0][r] + acc[t][1][r], 0.f);
                        sA2h[swzi(orow, orow * 256 + col)] = (_Float16)v;
                    }
                }
            }
            __syncthreads();
            // ---------- Phase C: L3 (a2 @ W3-hi^T) + RK combine (waves 0-3; kf in regs) ----------
            if (w < 4) {
                floatx4 aE = floatx4{rB3, rB3, rB3, rB3};
                floatx4 aO = floatx4{0.f, 0.f, 0.f, 0.f};
                #pragma unroll
                for (int kk = 0; kk < 8; ++kk) {
                    half8 ah = lds_frag256(sA2h, arow, kb + kk * 32);
                    half8 bh = *reinterpret_cast<const half8*>(
                        sW3h + ((kk * 4 + w) * 64 + lane) * 8);
                    floatx4& ac = (kk & 1) ? aO : aE;
                    ac = mfma16(ah, bh, ac);
                }
                // combine: z = y + H*(sum_{j<stg} c_j*kf_j + c_stg*k_new)
                #pragma unroll
                for (int r = 0; r < 4; ++r) {
                    int orow = q4 + r;
                    float kc = aE[r] + aO[r];
                    float s = CF[stg][stg] * kc;
                    #pragma unroll
                    for (int j = 0; j < stg; ++j)
                        s += CF[stg][j] * kf[j][r];
                    float z = yv[r] + H * s;
                    if (stg < 5) kf[stg][r] = kc;
                    else yv[r] = z;  // final combine of the step
                    sZh[swzi(orow, orow * 64 + ocol)] = (_Float16)z;
                }
            }
            __syncthreads();
        }
    }
    // ---- write y_final from registers ----
    if (w < 4) {
        #pragma unroll
        for (int r = 0; r < 4; ++r)
            out[(r0 + q4 + r) * 64 + ocol] = yv[r];
    }
}

extern "C" void kernel_launch(void* const* d_in, const int* in_sizes, int n_in,
                              void* d_out, int out_size, void* d_ws, size_t ws_size,
                              hipStream_t stream)
{
    const float* x0 = (const float*)d_in[0];
    const float* u  = (const float*)d_in[1];
    const float* W1 = (const float*)d_in[2];
    const float* b1 = (const float*)d_in[3];
    const float* W2 = (const float*)d_in[4];
    const float* b2 = (const float*)d_in[5];
    const float* W3 = (const float*)d_in[6];
    const float* b3 = (const float*)d_in[7];
    const int* t0 = (const int*)d_in[8];
    const int* t1 = (const int*)d_in[9];
    float* out = (float*)d_out;
    _Float16* ws = (_Float16*)d_ws;

    pack_weights<<<448, 256, 0, stream>>>(W1, W2, W3, ws);
    ode_kernel<<<64, 512, 0, stream>>>(x0, u, b1, b2, b3, ws, t0, t1, out);
}

// Round 11
// 320.539 us; speedup vs baseline: 4.4489x; 1.2167x over previous
//
#include <hip/hip_runtime.h>
#include <hip/hip_fp16.h>

typedef _Float16 half8 __attribute__((ext_vector_type(8)));
typedef _Float16 half2v __attribute__((ext_vector_type(2)));
typedef float floatx4 __attribute__((ext_vector_type(4)));

// d_ws half-element layout (packed fragment-major fp16)
#define W1YH_OFF 0        // W1 y-half (K=0..63)  hi: 256x64
#define W1YL_OFF 16384    //                      lo
#define W1UH_OFF 32768    // W1 u-half (K=64..127) hi
#define W1UL_OFF 49152    //                       lo
#define W2H_OFF  65536    // W2 hi: 256x256 (K sigma-permuted)
#define W2L_OFF  131072
#define W3H_OFF  196608   // W3 hi: 64x256 (K sigma-permuted)
#define W3L_OFF  212992

__device__ __forceinline__ floatx4 mfma16(half8 a, half8 b, floatx4 c) {
    return __builtin_amdgcn_mfma_f32_16x16x32_f16(a, b, c, 0, 0, 0);
}

// sigma: H-position q -> neuron. q = 32*wq + 2*c + s  <->  neuron 16*(2*wq+s)+c.
// Lets wave wq pack its two tile outputs (s=0,1) as one b32 at position 32wq+2c.
__device__ __forceinline__ int sigk(int k) {
    return 16 * (2 * (k >> 5) + (k & 1)) + ((k >> 1) & 15);
}

// Pack W[n][k] (row-major [N][K] fp32) into MFMA-B fragment-major fp16 hi/lo.
// W2/W3 K-dims are sigma-permuted to match the packed-activation layout.
__global__ __launch_bounds__(256) void pack_weights(
    const float* __restrict__ W1, const float* __restrict__ W2,
    const float* __restrict__ W3, _Float16* __restrict__ ws)
{
    int e = blockIdx.x * 256 + threadIdx.x;  // 0..114687
    const float* W;
    int K, NT, eb = e;
    if (e < 32768)      { W = W1; K = 128; NT = 16; }
    else if (e < 98304) { W = W2; K = 256; NT = 16; eb = e - 32768; }
    else                { W = W3; K = 256; NT = 4;  eb = e - 98304; }
    int j = eb & 7, l = (eb >> 3) & 63, t = eb >> 9;
    int tn = t % NT, kk = t / NT;
    int n = tn * 16 + (l & 15);
    int k = kk * 32 + ((l >> 4) * 8) + j;      // k-position in fragment space
    int kcol = (e < 32768) ? k : sigk(k);      // actual input column
    float wv = W[n * K + kcol];
    _Float16 hi = (_Float16)wv;
    _Float16 lo = (_Float16)(wv - (float)hi);
    int hoff, loff, fi;
    if (e < 32768) {            // W1: split y-half (kk<2) / u-half (kk>=2)
        if (kk < 2) { hoff = W1YH_OFF; loff = W1YL_OFF; fi = ((kk * 16 + tn) * 64 + l) * 8 + j; }
        else        { hoff = W1UH_OFF; loff = W1UL_OFF; fi = (((kk - 2) * 16 + tn) * 64 + l) * 8 + j; }
    } else if (e < 98304) { hoff = W2H_OFF; loff = W2L_OFF; fi = eb; }
    else                  { hoff = W3H_OFF; loff = W3L_OFF; fi = eb; }
    ws[hoff + fi] = hi;
    ws[loff + fi] = lo;
}

// Swizzle (half-element index XOR): ((row&7)<<3) ^ ((row&12)<<2)
// - b128 frag reads: per quarter-wave, 16B-nibble idx covers all 8 nibbles 2x
//   -> uniform 2 dwords/bank = minimum.
// - b32 packed C-frag stores: row-groups {r,4+r,8+r,12+r} get dword offsets
//   {0,24,16,8} -> each bank covered exactly 2x -> free 2-way.
// - XOR const is a multiple of 8 halfs (16B) -> b32/b128 alignment preserved.
__device__ __forceinline__ int swzi(int row, int lin) {
    return lin ^ (((row & 7) << 3) ^ ((row & 12) << 2));
}
__device__ __forceinline__ half8 lds_frag64(const _Float16* s, int row, int k0) {
    return *reinterpret_cast<const half8*>(s + swzi(row, row * 64 + k0));
}
__device__ __forceinline__ half8 lds_frag256(const _Float16* s, int row, int k0) {
    return *reinterpret_cast<const half8*>(s + swzi(row, row * 256 + k0));
}

__global__ __launch_bounds__(512) void ode_kernel(
    const float* __restrict__ x0, const float* __restrict__ u,
    const float* __restrict__ b1, const float* __restrict__ b2,
    const float* __restrict__ b3, const _Float16* __restrict__ ws,
    const int* __restrict__ t0p, const int* __restrict__ t1p,
    float* __restrict__ out)
{
    __shared__ _Float16 sW3h[16384];               // 32K: W3-hi packed (kk 4..7 used in loop)
    __shared__ _Float16 sA1h[4096];                // 8K  (activations fp16, sigma-packed)
    __shared__ _Float16 sA2h[4096];                // 8K
    __shared__ _Float16 sZh[1024];                 // 2K
    // total LDS = 51200 B

    const int tid = threadIdx.x;
    const int lane = tid & 63;
    const int w = tid >> 6;            // wave 0..7; owns N-tiles {2w, 2w+1}
    const int r0 = blockIdx.x * 16;
    const int arow = lane & 15;
    const int kb = (lane >> 4) * 8;
    const int q4 = (lane >> 4) * 4;
    const int t0n = 2 * w, t1n = 2 * w + 1;
    const int ocol = 16 * (w & 3) + arow;   // L3 C-frag col (valid on w<4)
    const int pbase = 32 * w + 2 * arow;    // packed store position base

    // ---- one-time LDS staging: W3-hi (2048 half8) ----
    {
        const half8* s3h = reinterpret_cast<const half8*>(ws + W3H_OFF);
        half8* d3h = reinterpret_cast<half8*>(sW3h);
        #pragma unroll
        for (int i = 0; i < 4; ++i)
            d3h[tid + 512 * i] = s3h[tid + 512 * i];
    }
    // ---- register-resident: W2-hi (2 tiles) + W1y-hi (2 tiles) + W3-hi kk0..3 ----
    half8 rW2h[2][8], rW1h[2][2], rW3h[4];
    {
        const half8* g2h = reinterpret_cast<const half8*>(ws + W2H_OFF);
        const half8* g1h = reinterpret_cast<const half8*>(ws + W1YH_OFF);
        const half8* g3h = reinterpret_cast<const half8*>(ws + W3H_OFF);
        #pragma unroll
        for (int kk = 0; kk < 8; ++kk) {
            rW2h[0][kk] = g2h[(kk * 16 + t0n) * 64 + lane];
            rW2h[1][kk] = g2h[(kk * 16 + t1n) * 64 + lane];
        }
        #pragma unroll
        for (int t = 0; t < 2; ++t)
            #pragma unroll
            for (int kk = 0; kk < 2; ++kk)
                rW1h[t][kk] = g1h[(kk * 16 + t0n + t) * 64 + lane];
        #pragma unroll
        for (int kk = 0; kk < 4; ++kk)
            rW3h[kk] = g3h[(kk * 4 + (w & 3)) * 64 + lane];
    }
    const float rB2a = b2[16 * t0n + arow], rB2b = b2[16 * t1n + arow];
    const float rB3 = b3[(w < 4) ? ocol : 0];

    // y state + k-history in C-frag registers (meaningful on w<4)
    float yv[4], kf[5][4];
    #pragma unroll
    for (int r = 0; r < 4; ++r)
        yv[r] = x0[(r0 + q4 + r) * 64 + ((w < 4) ? ocol : 0)];

    // ---- stage u hi into sA1h, u lo into sA2h (temp); z-y hi into sZh ----
    {
        int row = tid >> 5, c0 = (tid & 31) * 2;
        float u0v = u[(r0 + row) * 64 + c0], u1v = u[(r0 + row) * 64 + c0 + 1];
        float y0v = x0[(r0 + row) * 64 + c0], y1v = x0[(r0 + row) * 64 + c0 + 1];
        int idx = swzi(row, row * 64 + c0);
        _Float16 g0 = (_Float16)u0v, g1 = (_Float16)u1v;
        sA1h[idx] = g0; sA1h[idx + 1] = g1;
        sA2h[idx] = (_Float16)(u0v - (float)g0);
        sA2h[idx + 1] = (_Float16)(u1v - (float)g1);
        sZh[idx] = (_Float16)y0v;
        sZh[idx + 1] = (_Float16)y1v;
    }
    __syncthreads();

    // ---- precompute cU = u @ W1u^T + b1 (hi+lo inputs, one-time) ----
    float cU[2][4];
    {
        const half8* guh = reinterpret_cast<const half8*>(ws + W1UH_OFF);
        const half8* gul = reinterpret_cast<const half8*>(ws + W1UL_OFF);
        #pragma unroll
        for (int t = 0; t < 2; ++t) {
            int tn = t0n + t;
            float b1v = b1[16 * tn + arow];
            floatx4 a0 = floatx4{b1v, b1v, b1v, b1v};
            floatx4 a1v = floatx4{0.f, 0.f, 0.f, 0.f};
            #pragma unroll
            for (int kk = 0; kk < 2; ++kk) {
                half8 ah = lds_frag64(sA1h, arow, kb + kk * 32);
                half8 al = lds_frag64(sA2h, arow, kb + kk * 32);
                half8 bh = guh[(kk * 16 + tn) * 64 + lane];
                half8 bl = gul[(kk * 16 + tn) * 64 + lane];
                floatx4& ac = kk ? a1v : a0;
                ac = mfma16(ah, bh, ac);
                ac = mfma16(ah, bl, ac);
                ac = mfma16(al, bh, ac);
            }
            #pragma unroll
            for (int r = 0; r < 4; ++r) cU[t][r] = a0[r] + a1v[r];
        }
    }
    __syncthreads();  // done using sA1h/sA2h as u-staging

    const int nsteps = (t1p[0] - t0p[0]) * 60;  // h = 60s = 1/60 hr
    const float H = 1.0f / 60.0f;

    constexpr float CF[6][6] = {
        {0.161f, 0.f, 0.f, 0.f, 0.f, 0.f},
        {-0.008480655492356989f, 0.335480655492357f, 0.f, 0.f, 0.f, 0.f},
        {2.8971530571054935f, -6.359448489975075f, 4.3622954328695815f, 0.f, 0.f, 0.f},
        {5.325864828439257f, -11.748883564062828f, 7.4955393428898365f, -0.09249506636175525f, 0.f, 0.f},
        {5.86145544294642f, -12.92096931784711f, 8.159367898576159f, -0.071584973281401f, -0.028269050394068383f, 0.f},
        {0.09646076681806523f, 0.01f, 0.4798896504144996f, 1.379008574103742f, -3.290069515436081f, 2.324710524099774f},
    };

    #pragma unroll 1
    for (int step = 0; step < nsteps; ++step) {
        #pragma unroll
        for (int stg = 0; stg < 6; ++stg) {
            // ---------- Phase A: L1 (z_y @ W1y-hi^T + cU -> relu -> sA1h, packed b32) ----------
            {
                half8 zh0 = lds_frag64(sZh, arow, kb);
                half8 zh1 = lds_frag64(sZh, arow, kb + 32);
                floatx4 aT0 = floatx4{cU[0][0], cU[0][1], cU[0][2], cU[0][3]};
                aT0 = mfma16(zh0, rW1h[0][0], aT0);
                aT0 = mfma16(zh1, rW1h[0][1], aT0);
                floatx4 aT1 = floatx4{cU[1][0], cU[1][1], cU[1][2], cU[1][3]};
                aT1 = mfma16(zh0, rW1h[1][0], aT1);
                aT1 = mfma16(zh1, rW1h[1][1], aT1);
                #pragma unroll
                for (int r = 0; r < 4; ++r) {
                    int orow = q4 + r;
                    half2v pk;
                    pk[0] = (_Float16)fmaxf(aT0[r], 0.f);
                    pk[1] = (_Float16)fmaxf(aT1[r], 0.f);
                    *reinterpret_cast<half2v*>(sA1h + swzi(orow, orow * 256 + pbase)) = pk;
                }
            }
            __syncthreads();
            // ---------- Phase B: L2 (a1 @ W2-hi^T -> relu -> sA2h, packed b32) ----------
            {
                floatx4 acc[2][2];
                acc[0][0] = floatx4{rB2a, rB2a, rB2a, rB2a};
                acc[0][1] = floatx4{0.f, 0.f, 0.f, 0.f};
                acc[1][0] = floatx4{rB2b, rB2b, rB2b, rB2b};
                acc[1][1] = floatx4{0.f, 0.f, 0.f, 0.f};
                #pragma unroll
                for (int kk = 0; kk < 8; ++kk) {
                    half8 ah = lds_frag256(sA1h, arow, kb + kk * 32);
                    acc[0][kk & 1] = mfma16(ah, rW2h[0][kk], acc[0][kk & 1]);
                    acc[1][kk & 1] = mfma16(ah, rW2h[1][kk], acc[1][kk & 1]);
                }
                #pragma unroll
                for (int r = 0; r < 4; ++r) {
                    int orow = q4 + r;
                    half2v pk;
                    pk[0] = (_Float16)fmaxf(acc[0][0][r] + acc[0][1][r], 0.f);
                    pk[1] = (_Float16)fmaxf(acc[1][0][r] + acc[1][1][r], 0.f);
                    *reinterpret_cast<half2v*>(sA2h + swzi(orow, orow * 256 + pbase)) = pk;
                }
            }
            __syncthreads();
            // ---------- Phase C: L3 (a2 @ W3-hi^T) + RK combine (waves 0-3) ----------
            if (w < 4) {
                floatx4 aE = floatx4{rB3, rB3, rB3, rB3};
                floatx4 aO = floatx4{0.f, 0.f, 0.f, 0.f};
                #pragma unroll
                for (int kk = 0; kk < 8; ++kk) {
                    half8 ah = lds_frag256(sA2h, arow, kb + kk * 32);
                    half8 bh = (kk < 4) ? rW3h[kk]
                             : *reinterpret_cast<const half8*>(
                                   sW3h + ((kk * 4 + w) * 64 + lane) * 8);
                    floatx4& ac = (kk & 1) ? aO : aE;
                    ac = mfma16(ah, bh, ac);
                }
                // combine: z = y + H*(sum_{j<stg} c_j*kf_j + c_stg*k_new)
                #pragma unroll
                for (int r = 0; r < 4; ++r) {
                    int orow = q4 + r;
                    float kc = aE[r] + aO[r];
                    float s = CF[stg][stg] * kc;
                    #pragma unroll
                    for (int j = 0; j < stg; ++j)
                        s += CF[stg][j] * kf[j][r];
                    float z = yv[r] + H * s;
                    if (stg < 5) kf[stg][r] = kc;
                    else yv[r] = z;  // final combine of the step
                    sZh[swzi(orow, orow * 64 + ocol)] = (_Float16)z;
                }
            }
            __syncthreads();
        }
    }
    // ---- write y_final from registers ----
    if (w < 4) {
        #pragma unroll
        for (int r = 0; r < 4; ++r)
            out[(r0 + q4 + r) * 64 + ocol] = yv[r];
    }
}

extern "C" void kernel_launch(void* const* d_in, const int* in_sizes, int n_in,
                              void* d_out, int out_size, void* d_ws, size_t ws_size,
                              hipStream_t stream)
{
    const float* x0 = (const float*)d_in[0];
    const float* u  = (const float*)d_in[1];
    const float* W1 = (const float*)d_in[2];
    const float* b1 = (const float*)d_in[3];
    const float* W2 = (const float*)d_in[4];
    const float* b2 = (const float*)d_in[5];
    const float* W3 = (const float*)d_in[6];
    const float* b3 = (const float*)d_in[7];
    const int* t0 = (const int*)d_in[8];
    const int* t1 = (const int*)d_in[9];
    float* out = (float*)d_out;
    _Float16* ws = (_Float16*)d_ws;

    pack_weights<<<448, 256, 0, stream>>>(W1, W2, W3, ws);
    ode_kernel<<<64, 512, 0, stream>>>(x0, u, b1, b2, b3, ws, t0, t1, out);
}

// Round 12
// 297.867 us; speedup vs baseline: 4.7875x; 1.0761x over previous
//
#include <hip/hip_runtime.h>
#include <hip/hip_fp16.h>

typedef _Float16 half8 __attribute__((ext_vector_type(8)));
typedef _Float16 half2v __attribute__((ext_vector_type(2)));
typedef float floatx4 __attribute__((ext_vector_type(4)));

// d_ws half-element layout (packed fragment-major fp16)
#define W1YH_OFF 0        // W1 y-half (K=0..63)  hi: 256x64
#define W1YL_OFF 16384    //                      lo
#define W1UH_OFF 32768    // W1 u-half (K=64..127) hi
#define W1UL_OFF 49152    //                       lo
#define W2H_OFF  65536    // W2 hi: 256x256 (K sigma-permuted)
#define W2L_OFF  131072
#define W3H_OFF  196608   // W3 hi: 64x256 (K sigma-permuted)
#define W3L_OFF  212992

__device__ __forceinline__ floatx4 mfma16(half8 a, half8 b, floatx4 c) {
    return __builtin_amdgcn_mfma_f32_16x16x32_f16(a, b, c, 0, 0, 0);
}

// sigma: H-position q -> neuron. q = 32*wq + 2*c + s  <->  neuron 16*(2*wq+s)+c.
__device__ __forceinline__ int sigk(int k) {
    return 16 * (2 * (k >> 5) + (k & 1)) + ((k >> 1) & 15);
}

// Pack W[n][k] (row-major [N][K] fp32) into MFMA-B fragment-major fp16 hi/lo.
// W2/W3 K-dims are sigma-permuted to match the packed-activation layout.
__global__ __launch_bounds__(256) void pack_weights(
    const float* __restrict__ W1, const float* __restrict__ W2,
    const float* __restrict__ W3, _Float16* __restrict__ ws)
{
    int e = blockIdx.x * 256 + threadIdx.x;  // 0..114687
    const float* W;
    int K, NT, eb = e;
    if (e < 32768)      { W = W1; K = 128; NT = 16; }
    else if (e < 98304) { W = W2; K = 256; NT = 16; eb = e - 32768; }
    else                { W = W3; K = 256; NT = 4;  eb = e - 98304; }
    int j = eb & 7, l = (eb >> 3) & 63, t = eb >> 9;
    int tn = t % NT, kk = t / NT;
    int n = tn * 16 + (l & 15);
    int k = kk * 32 + ((l >> 4) * 8) + j;      // k-position in fragment space
    int kcol = (e < 32768) ? k : sigk(k);      // actual input column
    float wv = W[n * K + kcol];
    _Float16 hi = (_Float16)wv;
    _Float16 lo = (_Float16)(wv - (float)hi);
    int hoff, loff, fi;
    if (e < 32768) {            // W1: split y-half (kk<2) / u-half (kk>=2)
        if (kk < 2) { hoff = W1YH_OFF; loff = W1YL_OFF; fi = ((kk * 16 + tn) * 64 + l) * 8 + j; }
        else        { hoff = W1UH_OFF; loff = W1UL_OFF; fi = (((kk - 2) * 16 + tn) * 64 + l) * 8 + j; }
    } else if (e < 98304) { hoff = W2H_OFF; loff = W2L_OFF; fi = eb; }
    else                  { hoff = W3H_OFF; loff = W3L_OFF; fi = eb; }
    ws[hoff + fi] = hi;
    ws[loff + fi] = lo;
}

// Swizzle (half-element index XOR): ((row&7)<<3) ^ ((row&12)<<2)
// - b128 frag reads: per quarter-wave, 16B-nibble idx covers all 8 nibbles 2x
//   -> uniform 2 dwords/bank = structural minimum for b128.
// - b32 packed C-frag stores: row-groups map to distinct 32B octets -> free.
__device__ __forceinline__ int swzi(int row, int lin) {
    return lin ^ (((row & 7) << 3) ^ ((row & 12) << 2));
}
__device__ __forceinline__ half8 lds_frag64(const _Float16* s, int row, int k0) {
    return *reinterpret_cast<const half8*>(s + swzi(row, row * 64 + k0));
}
__device__ __forceinline__ half8 lds_frag256(const _Float16* s, int row, int k0) {
    return *reinterpret_cast<const half8*>(s + swzi(row, row * 256 + k0));
}

__global__ __launch_bounds__(512) void ode_kernel(
    const float* __restrict__ x0, const float* __restrict__ u,
    const float* __restrict__ b1, const float* __restrict__ b2,
    const float* __restrict__ b3, const _Float16* __restrict__ ws,
    const int* __restrict__ t0p, const int* __restrict__ t1p,
    float* __restrict__ out)
{
    __shared__ _Float16 sA1h[4096];                // 8K  (activations fp16, sigma-packed)
    __shared__ _Float16 sA2h[4096];                // 8K
    __shared__ _Float16 sZh[1024];                 // 2K
    // total LDS = 18432 B

    const int tid = threadIdx.x;
    const int lane = tid & 63;
    const int w = tid >> 6;            // wave 0..7; owns N-tiles {2w, 2w+1}
    const int r0 = blockIdx.x * 16;
    const int arow = lane & 15;
    const int kb = (lane >> 4) * 8;
    const int q4 = (lane >> 4) * 4;
    const int t0n = 2 * w, t1n = 2 * w + 1;
    const int ocol = 16 * (w & 3) + arow;   // L3 C-frag col (valid on w<4)
    const int pbase = 32 * w + 2 * arow;    // packed store position base

    // ---- register-resident: W2-hi (2 tiles) + W1y-hi (2 tiles) + W3-hi (1 tile, all kk) ----
    half8 rW2h[2][8], rW1h[2][2], rW3h[8];
    {
        const half8* g2h = reinterpret_cast<const half8*>(ws + W2H_OFF);
        const half8* g1h = reinterpret_cast<const half8*>(ws + W1YH_OFF);
        const half8* g3h = reinterpret_cast<const half8*>(ws + W3H_OFF);
        #pragma unroll
        for (int kk = 0; kk < 8; ++kk) {
            rW2h[0][kk] = g2h[(kk * 16 + t0n) * 64 + lane];
            rW2h[1][kk] = g2h[(kk * 16 + t1n) * 64 + lane];
        }
        #pragma unroll
        for (int t = 0; t < 2; ++t)
            #pragma unroll
            for (int kk = 0; kk < 2; ++kk)
                rW1h[t][kk] = g1h[(kk * 16 + t0n + t) * 64 + lane];
        #pragma unroll
        for (int kk = 0; kk < 8; ++kk)
            rW3h[kk] = g3h[(kk * 4 + (w & 3)) * 64 + lane];
    }
    const float rB2a = b2[16 * t0n + arow], rB2b = b2[16 * t1n + arow];
    const float rB3 = b3[(w < 4) ? ocol : 0];

    // y state + k-history in C-frag registers (meaningful on w<4)
    float yv[4], kf[5][4];
    #pragma unroll
    for (int r = 0; r < 4; ++r)
        yv[r] = x0[(r0 + q4 + r) * 64 + ((w < 4) ? ocol : 0)];

    // ---- stage u hi into sA1h, u lo into sA2h (temp); z-y hi into sZh ----
    {
        int row = tid >> 5, c0 = (tid & 31) * 2;
        float u0v = u[(r0 + row) * 64 + c0], u1v = u[(r0 + row) * 64 + c0 + 1];
        float y0v = x0[(r0 + row) * 64 + c0], y1v = x0[(r0 + row) * 64 + c0 + 1];
        int idx = swzi(row, row * 64 + c0);
        _Float16 g0 = (_Float16)u0v, g1 = (_Float16)u1v;
        sA1h[idx] = g0; sA1h[idx + 1] = g1;
        sA2h[idx] = (_Float16)(u0v - (float)g0);
        sA2h[idx + 1] = (_Float16)(u1v - (float)g1);
        sZh[idx] = (_Float16)y0v;
        sZh[idx + 1] = (_Float16)y1v;
    }
    __syncthreads();

    // ---- precompute cU = u @ W1u^T + b1 (hi+lo inputs, one-time) ----
    float cU[2][4];
    {
        const half8* guh = reinterpret_cast<const half8*>(ws + W1UH_OFF);
        const half8* gul = reinterpret_cast<const half8*>(ws + W1UL_OFF);
        #pragma unroll
        for (int t = 0; t < 2; ++t) {
            int tn = t0n + t;
            float b1v = b1[16 * tn + arow];
            floatx4 a0 = floatx4{b1v, b1v, b1v, b1v};
            floatx4 a1v = floatx4{0.f, 0.f, 0.f, 0.f};
            #pragma unroll
            for (int kk = 0; kk < 2; ++kk) {
                half8 ah = lds_frag64(sA1h, arow, kb + kk * 32);
                half8 al = lds_frag64(sA2h, arow, kb + kk * 32);
                half8 bh = guh[(kk * 16 + tn) * 64 + lane];
                half8 bl = gul[(kk * 16 + tn) * 64 + lane];
                floatx4& ac = kk ? a1v : a0;
                ac = mfma16(ah, bh, ac);
                ac = mfma16(ah, bl, ac);
                ac = mfma16(al, bh, ac);
            }
            #pragma unroll
            for (int r = 0; r < 4; ++r) cU[t][r] = a0[r] + a1v[r];
        }
    }
    __syncthreads();  // done using sA1h/sA2h as u-staging

    const int nsteps = (t1p[0] - t0p[0]) * 60;  // h = 60s = 1/60 hr
    const float H = 1.0f / 60.0f;

    constexpr float CF[6][6] = {
        {0.161f, 0.f, 0.f, 0.f, 0.f, 0.f},
        {-0.008480655492356989f, 0.335480655492357f, 0.f, 0.f, 0.f, 0.f},
        {2.8971530571054935f, -6.359448489975075f, 4.3622954328695815f, 0.f, 0.f, 0.f},
        {5.325864828439257f, -11.748883564062828f, 7.4955393428898365f, -0.09249506636175525f, 0.f, 0.f},
        {5.86145544294642f, -12.92096931784711f, 8.159367898576159f, -0.071584973281401f, -0.028269050394068383f, 0.f},
        {0.09646076681806523f, 0.01f, 0.4798896504144996f, 1.379008574103742f, -3.290069515436081f, 2.324710524099774f},
    };

    #pragma unroll 1
    for (int step = 0; step < nsteps; ++step) {
        #pragma unroll
        for (int stg = 0; stg < 6; ++stg) {
            // ---------- Phase A: L1 (z_y @ W1y-hi^T + cU -> relu -> sA1h, packed b32) ----------
            {
                half8 zh0 = lds_frag64(sZh, arow, kb);
                half8 zh1 = lds_frag64(sZh, arow, kb + 32);
                floatx4 aT0 = floatx4{cU[0][0], cU[0][1], cU[0][2], cU[0][3]};
                aT0 = mfma16(zh0, rW1h[0][0], aT0);
                aT0 = mfma16(zh1, rW1h[0][1], aT0);
                floatx4 aT1 = floatx4{cU[1][0], cU[1][1], cU[1][2], cU[1][3]};
                aT1 = mfma16(zh0, rW1h[1][0], aT1);
                aT1 = mfma16(zh1, rW1h[1][1], aT1);
                #pragma unroll
                for (int r = 0; r < 4; ++r) {
                    int orow = q4 + r;
                    half2v pk;
                    pk[0] = (_Float16)fmaxf(aT0[r], 0.f);
                    pk[1] = (_Float16)fmaxf(aT1[r], 0.f);
                    *reinterpret_cast<half2v*>(sA1h + swzi(orow, orow * 256 + pbase)) = pk;
                }
            }
            __syncthreads();
            // ---------- Phase B: L2 (a1 @ W2-hi^T -> relu -> sA2h, packed b32) ----------
            {
                floatx4 acc[2][2];
                acc[0][0] = floatx4{rB2a, rB2a, rB2a, rB2a};
                acc[0][1] = floatx4{0.f, 0.f, 0.f, 0.f};
                acc[1][0] = floatx4{rB2b, rB2b, rB2b, rB2b};
                acc[1][1] = floatx4{0.f, 0.f, 0.f, 0.f};
                #pragma unroll
                for (int kk = 0; kk < 8; ++kk) {
                    half8 ah = lds_frag256(sA1h, arow, kb + kk * 32);
                    acc[0][kk & 1] = mfma16(ah, rW2h[0][kk], acc[0][kk & 1]);
                    acc[1][kk & 1] = mfma16(ah, rW2h[1][kk], acc[1][kk & 1]);
                }
                #pragma unroll
                for (int r = 0; r < 4; ++r) {
                    int orow = q4 + r;
                    half2v pk;
                    pk[0] = (_Float16)fmaxf(acc[0][0][r] + acc[0][1][r], 0.f);
                    pk[1] = (_Float16)fmaxf(acc[1][0][r] + acc[1][1][r], 0.f);
                    *reinterpret_cast<half2v*>(sA2h + swzi(orow, orow * 256 + pbase)) = pk;
                }
            }
            __syncthreads();
            // ---------- Phase C: L3 (a2 @ W3-hi^T, all-reg B) + RK combine (waves 0-3) ----------
            if (w < 4) {
                // base = y + H*sum_{j<stg} c_j*kf_j  -- independent of this stage's
                // MFMAs; computed up front so the VALU work overlaps the matrix pipe.
                float base[4];
                #pragma unroll
                for (int r = 0; r < 4; ++r) {
                    float s = 0.f;
                    #pragma unroll
                    for (int j = 0; j < stg; ++j)
                        s += CF[stg][j] * kf[j][r];
                    base[r] = yv[r] + H * s;
                }
                floatx4 aE = floatx4{rB3, rB3, rB3, rB3};
                floatx4 aO = floatx4{0.f, 0.f, 0.f, 0.f};
                #pragma unroll
                for (int kk = 0; kk < 8; ++kk) {
                    half8 ah = lds_frag256(sA2h, arow, kb + kk * 32);
                    floatx4& ac = (kk & 1) ? aO : aE;
                    ac = mfma16(ah, rW3h[kk], ac);
                }
                #pragma unroll
                for (int r = 0; r < 4; ++r) {
                    int orow = q4 + r;
                    float kc = aE[r] + aO[r];
                    if (stg < 5) kf[stg][r] = kc;
                    float z = base[r] + (H * CF[stg][stg]) * kc;
                    if (stg == 5) yv[r] = z;  // final combine of the step
                    sZh[swzi(orow, orow * 64 + ocol)] = (_Float16)z;
                }
            }
            __syncthreads();
        }
    }
    // ---- write y_final from registers ----
    if (w < 4) {
        #pragma unroll
        for (int r = 0; r < 4; ++r)
            out[(r0 + q4 + r) * 64 + ocol] = yv[r];
    }
}

extern "C" void kernel_launch(void* const* d_in, const int* in_sizes, int n_in,
                              void* d_out, int out_size, void* d_ws, size_t ws_size,
                              hipStream_t stream)
{
    const float* x0 = (const float*)d_in[0];
    const float* u  = (const float*)d_in[1];
    const float* W1 = (const float*)d_in[2];
    const float* b1 = (const float*)d_in[3];
    const float* W2 = (const float*)d_in[4];
    const float* b2 = (const float*)d_in[5];
    const float* W3 = (const float*)d_in[6];
    const float* b3 = (const float*)d_in[7];
    const int* t0 = (const int*)d_in[8];
    const int* t1 = (const int*)d_in[9];
    float* out = (float*)d_out;
    _Float16* ws = (_Float16*)d_ws;

    pack_weights<<<448, 256, 0, stream>>>(W1, W2, W3, ws);
    ode_kernel<<<64, 512, 0, stream>>>(x0, u, b1, b2, b3, ws, t0, t1, out);
}